// Round 5
// baseline (693.611 us; speedup 1.0000x reference)
//
#include <hip/hip_runtime.h>
#include <hip/hip_fp16.h>

// Problem constants (fixed by the reference)
constexpr int NN = 100000;          // nodes
constexpr int EE = 1600000;         // edges (without self loops)
constexpr int ET = EE + NN;         // edges + self loops
constexpr float NEG = 0.2f;

typedef _Float16 f16x8 __attribute__((ext_vector_type(8)));
typedef _Float16 f16x4 __attribute__((ext_vector_type(4)));
typedef float    f32x4 __attribute__((ext_vector_type(4)));

// ---------------------------------------------------------------------------
// CSR build: histogram -> scan -> scatter (csr only; dst is implicit via rs)
// ---------------------------------------------------------------------------
__global__ __launch_bounds__(256) void k_count(const int* __restrict__ ei, int* __restrict__ deg) {
    int i = blockIdx.x * 256 + threadIdx.x;
    if (i >= ET) return;
    int dst = (i < EE) ? ei[EE + i] : (i - EE);
    atomicAdd(&deg[dst], 1);
}

__global__ __launch_bounds__(256) void k_part(const int* __restrict__ deg, int* __restrict__ part) {
    __shared__ int sh[256];
    int i = blockIdx.x * 256 + threadIdx.x;
    sh[threadIdx.x] = (i < NN) ? deg[i] : 0;
    __syncthreads();
    for (int o = 128; o; o >>= 1) {
        if (threadIdx.x < o) sh[threadIdx.x] += sh[threadIdx.x + o];
        __syncthreads();
    }
    if (threadIdx.x == 0) part[blockIdx.x] = sh[0];
}

__global__ __launch_bounds__(512) void k_scanp(int* __restrict__ part, int nb) {
    __shared__ int sh[512];
    int t = threadIdx.x;
    int v = (t < nb) ? part[t] : 0;
    sh[t] = v;
    __syncthreads();
    for (int o = 1; o < 512; o <<= 1) {
        int u = (t >= o) ? sh[t - o] : 0;
        __syncthreads();
        sh[t] += u;
        __syncthreads();
    }
    if (t < nb) part[t] = sh[t] - v;   // exclusive
}

__global__ __launch_bounds__(256) void k_scan(const int* __restrict__ deg, const int* __restrict__ part,
                                              int* __restrict__ rs, int* __restrict__ cur) {
    __shared__ int sh[256];
    int t = threadIdx.x;
    int i = blockIdx.x * 256 + t;
    int v = (i < NN) ? deg[i] : 0;
    sh[t] = v;
    __syncthreads();
    for (int o = 1; o < 256; o <<= 1) {
        int u = (t >= o) ? sh[t - o] : 0;
        __syncthreads();
        sh[t] += u;
        __syncthreads();
    }
    int incl = sh[t];
    int base = part[blockIdx.x];
    if (i < NN) {
        rs[i]  = base + incl - v;
        cur[i] = base + incl - v;
        if (i == NN - 1) rs[NN] = base + incl;
    }
}

__global__ __launch_bounds__(256) void k_scatter(const int* __restrict__ ei, int* __restrict__ cur,
                                                 int* __restrict__ csr) {
    int i = blockIdx.x * 256 + threadIdx.x;
    if (i >= ET) return;
    int src, dst;
    if (i < EE) { src = ei[i]; dst = ei[EE + i]; }
    else        { src = i - EE; dst = i - EE; }
    int pos = atomicAdd(&cur[dst], 1);
    csr[pos] = src;
}

// ---------------------------------------------------------------------------
// MFMA GEMM: xp = x @ W (fp16 inputs to matrix core, fp32 accumulate).
// OUT_MODE 1: plain fp16 row of C halves.
// ---------------------------------------------------------------------------
template <int K, int C, int OUT_MODE, bool SRCF32>
__global__ __launch_bounds__(256) void gemm_mfma(const void* __restrict__ xv, const float* __restrict__ W,
                                                 __half* __restrict__ xp, int n, int set_off) {
    constexpr int KC  = 64;          // K-chunk per stage
    constexpr int AST = KC + 8;      // padded LDS stride (halves)
    constexpr int NT  = C / 16;      // 16-col tiles
    constexpr int NST = K / KC;      // stages
    __shared__ _Float16 a_lds[128 * AST];
    __shared__ _Float16 w_lds[C * AST];

    const int tid  = threadIdx.x;
    const int w    = tid >> 6;
    const int lane = tid & 63;
    const int quad = lane >> 4;
    const int l16  = lane & 15;
    const long r0  = (long)blockIdx.x * 128;

    f32x4 acc[2][NT];
#pragma unroll
    for (int s = 0; s < 2; s++)
#pragma unroll
        for (int t = 0; t < NT; t++) acc[s][t] = (f32x4){0.f, 0.f, 0.f, 0.f};

    for (int st = 0; st < NST; ++st) {
        const int k0 = st * KC;
        // stage A: 128 rows x KC halves (convert fp32->fp16 if needed)
        for (int i = tid; i < 128 * (KC / 4); i += 256) {
            int r = i / (KC / 4);
            int q = i % (KC / 4);
            long row = r0 + r;
            f16x4 hv = (f16x4){0, 0, 0, 0};
            if (row < n) {
                if (SRCF32) {
                    float4 v = ((const float4*)xv)[row * (K / 4) + (k0 / 4) + q];
                    hv = (f16x4){(_Float16)v.x, (_Float16)v.y, (_Float16)v.z, (_Float16)v.w};
                } else {
                    hv = ((const f16x4*)xv)[row * (K / 4) + (k0 / 4) + q];
                }
            }
            *(f16x4*)&a_lds[r * AST + q * 4] = hv;
        }
        // stage W^T: w_lds[n][k] from W[k][n] (coalesced global reads over n)
        for (int i = tid; i < C * (KC / 4); i += 256) {
            int nn = i / (KC / 4);
            int kq = i % (KC / 4);
            f16x4 hv;
            hv.x = (_Float16)W[(long)(k0 + kq * 4 + 0) * C + nn];
            hv.y = (_Float16)W[(long)(k0 + kq * 4 + 1) * C + nn];
            hv.z = (_Float16)W[(long)(k0 + kq * 4 + 2) * C + nn];
            hv.w = (_Float16)W[(long)(k0 + kq * 4 + 3) * C + nn];
            *(f16x4*)&w_lds[nn * AST + kq * 4] = hv;
        }
        __syncthreads();

#pragma unroll
        for (int ks = 0; ks < KC; ks += 32) {
            f16x8 a0 = *(const f16x8*)&a_lds[(w * 32 + l16) * AST + ks + quad * 8];
            f16x8 a1 = *(const f16x8*)&a_lds[(w * 32 + 16 + l16) * AST + ks + quad * 8];
#pragma unroll
            for (int t = 0; t < NT; t++) {
                f16x8 b = *(const f16x8*)&w_lds[(t * 16 + l16) * AST + ks + quad * 8];
                acc[0][t] = __builtin_amdgcn_mfma_f32_16x16x32_f16(a0, b, acc[0][t], 0, 0, 0);
                acc[1][t] = __builtin_amdgcn_mfma_f32_16x16x32_f16(a1, b, acc[1][t], 0, 0, 0);
            }
        }
        __syncthreads();
    }

    // epilogue: C/D layout col=l16, row=quad*4+reg
#pragma unroll
    for (int sub = 0; sub < 2; sub++) {
        long rb = r0 + w * 32 + sub * 16 + quad * 4;
#pragma unroll
        for (int t = 0; t < NT; t++) {
            int c = t * 16 + l16;
#pragma unroll
            for (int rg = 0; rg < 4; rg++) {
                long row = rb + rg;
                if (row < n) {
                    __half hv = __float2half(acc[sub][t][rg]);
                    if (OUT_MODE == 0)
                        xp[row * 256 + ((c >> 1) << 2) + (c & 1) + set_off] = hv;
                    else
                        xp[row * (long)C + c] = hv;
                }
            }
        }
    }
}

// ---------------------------------------------------------------------------
// Attention coefficients for conv1 from the two plain fp16 feature arrays.
// Thread per (v, head). att_sp[v*4+h] = <xp_p[v], as1[h]>, etc.
// ---------------------------------------------------------------------------
__global__ __launch_bounds__(256) void attn1_plain(const __half2* __restrict__ xp_p,
                                                   const __half2* __restrict__ xp_g,
                                                   const float* __restrict__ as_w, const float* __restrict__ ad_w,
                                                   float* __restrict__ att_sp, float* __restrict__ att_dp,
                                                   float* __restrict__ att_sg, float* __restrict__ att_dg, int n) {
    int idx = blockIdx.x * 256 + threadIdx.x;
    if (idx >= n * 4) return;
    int v = idx >> 2, hh = idx & 3;
    const __half2* rp = xp_p + (long)v * 64 + hh * 16;
    const __half2* rg = xp_g + (long)v * 64 + hh * 16;
    const float* a1 = as_w + hh * 32;
    const float* a2 = ad_w + hh * 32;
    float sp1 = 0.f, sp2 = 0.f, sg1 = 0.f, sg2 = 0.f;
#pragma unroll
    for (int t = 0; t < 16; t++) {
        float2 fp = __half22float2(rp[t]);
        float2 fg = __half22float2(rg[t]);
        float2 w1 = *(const float2*)(a1 + 2 * t);
        float2 w2 = *(const float2*)(a2 + 2 * t);
        sp1 += fp.x * w1.x + fp.y * w1.y;
        sp2 += fp.x * w2.x + fp.y * w2.y;
        sg1 += fg.x * w1.x + fg.y * w1.y;
        sg2 += fg.x * w2.x + fg.y * w2.y;
    }
    att_sp[idx] = sp1; att_dp[idx] = sp2;
    att_sg[idx] = sg1; att_dg[idx] = sg2;
}

// attention for conv2 (H=1, C=64), fp16 xp
__global__ __launch_bounds__(256) void attn2_kernel(const __half2* __restrict__ xp,
                                                    const float* __restrict__ as_w, const float* __restrict__ ad_w,
                                                    float* __restrict__ asrc, float* __restrict__ adst, int n) {
    int v = blockIdx.x * 256 + threadIdx.x;
    if (v >= n) return;
    const __half2* p = xp + (long)v * 32;
    float s1 = 0.f, s2 = 0.f;
#pragma unroll
    for (int c = 0; c < 32; c++) {
        float2 xv = __half22float2(p[c]);
        float2 w1 = *(const float2*)(as_w + 2 * c);
        float2 w2 = *(const float2*)(ad_w + 2 * c);
        s1 += xv.x * w1.x + xv.y * w1.y;
        s2 += xv.x * w2.x + xv.y * w2.y;
    }
    asrc[v] = s1;
    adst[v] = s2;
}

// ---------------------------------------------------------------------------
// Per-edge exp-weights for conv1, CSR-ordered (no dstv needed): one 16-lane
// group per dst node. dst scores broadcast from att_d*[v]; src scores
// gathered from the L2-resident 1.6MB tables; csr reads + wb writes
// sequential/coalesced. Writes wb_p[j][4] and wb_g[j][4] (16B/edge each).
// ---------------------------------------------------------------------------
__global__ __launch_bounds__(256) void w1prep_node(const int* __restrict__ rs, const int* __restrict__ csr,
                                                   const float4* __restrict__ att_sp4, const float4* __restrict__ att_dp4,
                                                   const float4* __restrict__ att_sg4, const float4* __restrict__ att_dg4,
                                                   float4* __restrict__ wbp4, float4* __restrict__ wbg4) {
    int v = blockIdx.x * 16 + (threadIdx.x >> 4);
    if (v >= NN) return;
    int sl = threadIdx.x & 15;
    int e0 = rs[v], e1 = rs[v + 1];
    float4 dp = att_dp4[v], dg = att_dg4[v];
    auto w = [](float e) { e = (e > 0.f) ? e : NEG * e; return __expf(e); };
    for (int j = e0 + sl; j < e1; j += 16) {
        int s = csr[j];
        float4 sp = att_sp4[s], sg = att_sg4[s];
        float4 wp, wg;
        wp.x = w(sp.x + dp.x); wp.y = w(sp.y + dp.y);
        wp.z = w(sp.z + dp.z); wp.w = w(sp.w + dp.w);
        wg.x = w(sg.x + dg.x); wg.y = w(sg.y + dg.y);
        wg.z = w(sg.z + dg.z); wg.w = w(sg.w + dg.w);
        wbp4[j] = wp;
        wbg4[j] = wg;
    }
}

// ---------------------------------------------------------------------------
// conv1 single-set pass. Working-set split: this pass reads ONE 25.6MB
// feature array (256B rows) so L2 re-reference distance halves vs a packed
// 51MB layout -> higher hit rate -> fewer counted bytes (proven wall is
// bytes/3.85TB/s). One wave per dst node; quarter-wave qw handles edges
// j+4k+qw; lane m (0..15) gathers 16B = channels 8m..8m+7. Weights streamed
// (4B/lane/edge from wb). 16-edge full chunks (4 gathers in flight), 4-edge
// clamped tail. Combine via shfl_xor(16,32); qw==0 lanes write uint4 of 8
// fp16 (bias+ReLU applied) into hbuf[v*256 + off + 8m].
// ---------------------------------------------------------------------------
__global__ __launch_bounds__(256) void conv1_pass(const int* __restrict__ rs, const int* __restrict__ csr,
                                                  const uint4* __restrict__ xp,
                                                  const float* __restrict__ wb,
                                                  const float* __restrict__ bias,
                                                  __half* __restrict__ out, int off) {
    int v = blockIdx.x * 4 + (threadIdx.x >> 6);
    if (v >= NN) return;
    int lane = threadIdx.x & 63;
    int qw = lane >> 4;                // quarter-wave: edge offset
    int m = lane & 15;                 // channels 8m..8m+7
    int hd = m >> 2;                   // head index for this lane's channels
    int e0 = rs[v], e1 = rs[v + 1];

    float a[8];
#pragma unroll
    for (int i = 0; i < 8; i++) a[i] = 0.f;
    float d = 0.f;

    int j = e0;
    // full chunks: 16 edges, 4 gathers in flight, no predication
    for (; j + 16 <= e1; j += 16) {
        int s[4]; float w[4]; uint4 r[4];
#pragma unroll
        for (int k = 0; k < 4; k++) s[k] = csr[j + 4 * k + qw];
#pragma unroll
        for (int k = 0; k < 4; k++) w[k] = wb[(j + 4 * k + qw) * 4 + hd];
#pragma unroll
        for (int k = 0; k < 4; k++) r[k] = xp[(long)s[k] * 16 + m];
#pragma unroll
        for (int k = 0; k < 4; k++) {
            d += w[k];
            float2 f0 = __half22float2(*(__half2*)&r[k].x);
            float2 f1 = __half22float2(*(__half2*)&r[k].y);
            float2 f2 = __half22float2(*(__half2*)&r[k].z);
            float2 f3 = __half22float2(*(__half2*)&r[k].w);
            a[0] += w[k] * f0.x; a[1] += w[k] * f0.y;
            a[2] += w[k] * f1.x; a[3] += w[k] * f1.y;
            a[4] += w[k] * f2.x; a[5] += w[k] * f2.y;
            a[6] += w[k] * f3.x; a[7] += w[k] * f3.y;
        }
    }
    // tail: 4 edges per iteration, clamped duplicate gathers with zero weight
    for (; j < e1; j += 4) {
        int jj = j + qw;
        int jc = (jj < e1) ? jj : (e1 - 1);
        int s = csr[jc];
        float w = (jj < e1) ? wb[jc * 4 + hd] : 0.f;
        uint4 r = xp[(long)s * 16 + m];
        d += w;
        float2 f0 = __half22float2(*(__half2*)&r.x);
        float2 f1 = __half22float2(*(__half2*)&r.y);
        float2 f2 = __half22float2(*(__half2*)&r.z);
        float2 f3 = __half22float2(*(__half2*)&r.w);
        a[0] += w * f0.x; a[1] += w * f0.y;
        a[2] += w * f1.x; a[3] += w * f1.y;
        a[4] += w * f2.x; a[5] += w * f2.y;
        a[6] += w * f3.x; a[7] += w * f3.y;
    }

    // combine the four quarters (disjoint edge subsets)
#pragma unroll
    for (int i = 0; i < 8; i++) {
        a[i] += __shfl_xor(a[i], 16);
        a[i] += __shfl_xor(a[i], 32);
    }
    d += __shfl_xor(d, 16);
    d += __shfl_xor(d, 32);

    if (qw == 0) {
        float inv = 1.0f / d;
        const float4* b4 = (const float4*)bias;
        float4 bA = b4[2 * m], bB = b4[2 * m + 1];
        __half2 o01 = __floats2half2_rn(fmaxf(a[0] * inv + bA.x, 0.f), fmaxf(a[1] * inv + bA.y, 0.f));
        __half2 o23 = __floats2half2_rn(fmaxf(a[2] * inv + bA.z, 0.f), fmaxf(a[3] * inv + bA.w, 0.f));
        __half2 o45 = __floats2half2_rn(fmaxf(a[4] * inv + bB.x, 0.f), fmaxf(a[5] * inv + bB.y, 0.f));
        __half2 o67 = __floats2half2_rn(fmaxf(a[6] * inv + bB.z, 0.f), fmaxf(a[7] * inv + bB.w, 0.f));
        uint4 st;
        st.x = *(unsigned int*)&o01;
        st.y = *(unsigned int*)&o23;
        st.z = *(unsigned int*)&o45;
        st.w = *(unsigned int*)&o67;
        *(uint4*)(out + (long)v * 256 + off + 8 * m) = st;
    }
}

// ---------------------------------------------------------------------------
// Single-pass conv2 edge kernel (H=1, C=64, fp16 xp). Weight inline from
// asrc[s] (400KB) + adst[v] register. Quarter-waves; 16-edge full chunks.
// ---------------------------------------------------------------------------
__global__ __launch_bounds__(256) void conv2_edge(const int* __restrict__ rs, const int* __restrict__ csr,
                                                  const __half* __restrict__ xp,
                                                  const float* __restrict__ asrc,
                                                  const float* __restrict__ adst,
                                                  const float* __restrict__ bias,
                                                  float* __restrict__ out) {
    int v = blockIdx.x * 4 + (threadIdx.x >> 6);
    if (v >= NN) return;
    int lane = threadIdx.x & 63;
    int qw = lane >> 4;                // quarter-wave: edge offset
    int m = lane & 15;                 // channels 4m..4m+3
    int e0 = rs[v], e1 = rs[v + 1];
    const uint2* xp2 = (const uint2*)xp;

    float adv = adst[v];
    auto lrexp = [](float e) { e = (e > 0.f) ? e : NEG * e; return __expf(e); };

    float a0 = 0.f, a1 = 0.f, a2 = 0.f, a3 = 0.f, d = 0.f;

    int j = e0;
    // full chunks: 16 edges, 4 gathers in flight, no predication
    for (; j + 16 <= e1; j += 16) {
        int s[4]; float av[4]; uint2 r[4];
#pragma unroll
        for (int k = 0; k < 4; k++) s[k] = csr[j + 4 * k + qw];
#pragma unroll
        for (int k = 0; k < 4; k++) av[k] = asrc[s[k]];
#pragma unroll
        for (int k = 0; k < 4; k++) r[k] = xp2[(long)s[k] * 16 + m];
#pragma unroll
        for (int k = 0; k < 4; k++) {
            float w = lrexp(av[k] + adv);
            d += w;
            float2 x01 = __half22float2(*(__half2*)&r[k].x);
            float2 x23 = __half22float2(*(__half2*)&r[k].y);
            a0 += w * x01.x; a1 += w * x01.y;
            a2 += w * x23.x; a3 += w * x23.y;
        }
    }
    // tail: 4 edges per iteration, clamped
    for (; j < e1; j += 4) {
        int jj = j + qw;
        int jc = (jj < e1) ? jj : (e1 - 1);
        int s = csr[jc];
        float av = asrc[s];
        uint2 r = xp2[(long)s * 16 + m];
        float w = (jj < e1) ? lrexp(av + adv) : 0.f;
        d += w;
        float2 x01 = __half22float2(*(__half2*)&r.x);
        float2 x23 = __half22float2(*(__half2*)&r.y);
        a0 += w * x01.x; a1 += w * x01.y;
        a2 += w * x23.x; a3 += w * x23.y;
    }

    // combine the four quarters
    a0 += __shfl_xor(a0, 16); a1 += __shfl_xor(a1, 16);
    a2 += __shfl_xor(a2, 16); a3 += __shfl_xor(a3, 16);
    d  += __shfl_xor(d, 16);
    a0 += __shfl_xor(a0, 32); a1 += __shfl_xor(a1, 32);
    a2 += __shfl_xor(a2, 32); a3 += __shfl_xor(a3, 32);
    d  += __shfl_xor(d, 32);

    if (qw == 0) {
        float inv = 1.0f / d;
        float4 b4 = *(const float4*)&bias[4 * m];
        float4 o;
        o.x = a0 * inv + b4.x;
        o.y = a1 * inv + b4.y;
        o.z = a2 * inv + b4.z;
        o.w = a3 * inv + b4.w;
        *(float4*)&out[(long)v * 64 + 4 * m] = o;
    }
}

// ---------------------------------------------------------------------------
// Launch
// ---------------------------------------------------------------------------
extern "C" void kernel_launch(void* const* d_in, const int* in_sizes, int n_in,
                              void* d_out, int out_size, void* d_ws, size_t ws_size,
                              hipStream_t stream) {
    const float* x_ppi = (const float*)d_in[0];
    const float* x_go  = (const float*)d_in[1];
    const int*   ei    = (const int*)d_in[2];
    const float* W1    = (const float*)d_in[3];
    const float* as1   = (const float*)d_in[4];
    const float* ad1   = (const float*)d_in[5];
    const float* b1    = (const float*)d_in[6];
    const float* W2    = (const float*)d_in[7];
    const float* as2   = (const float*)d_in[8];
    const float* ad2   = (const float*)d_in[9];
    const float* b2    = (const float*)d_in[10];
    float* out = (float*)d_out;

    char* ws = (char*)d_ws;
    size_t off = 0;
    auto alloc = [&](size_t bytes) -> void* {
        void* p = ws + off;
        off = (off + bytes + 255) & ~(size_t)255;
        return p;
    };
    int* deg     = (int*)alloc((size_t)NN * 4);
    int* rs      = (int*)alloc((size_t)(NN + 1) * 4);
    int* cur     = (int*)alloc((size_t)NN * 4);
    int* part    = (int*)alloc(512 * 4);
    int* csr     = (int*)alloc((size_t)ET * 4);
    __half* xp_p = (__half*)alloc((size_t)NN * 128 * 2);   // conv1 p-set features
    __half* xp_g = (__half*)alloc((size_t)NN * 128 * 2);   // conv1 g-set features
    __half* xp2  = (__half*)alloc((size_t)NN * 64 * 2);    // conv2 features fp16
    float* attsp = (float*)alloc((size_t)NN * 4 * 4);
    float* attdp = (float*)alloc((size_t)NN * 4 * 4);
    float* attsg = (float*)alloc((size_t)NN * 4 * 4);
    float* attdg = (float*)alloc((size_t)NN * 4 * 4);
    float* asr2  = (float*)alloc((size_t)NN * 4);
    float* ads2  = (float*)alloc((size_t)NN * 4);
    float* wbp   = (float*)alloc((size_t)ET * 16);         // 4 fp32 weights/edge (p)
    float* wbg   = (float*)alloc((size_t)ET * 16);         // 4 fp32 weights/edge (g)
    __half* hbuf = (__half*)alloc((size_t)NN * 256 * 2);   // conv1 output, fp16
    (void)ws_size; (void)in_sizes; (void)n_in; (void)out_size;

    const int NB = (NN + 255) / 256;        // 391
    const int EB = (ET + 255) / 256;        // 6641
    const int GB = (NN + 127) / 128;        // 782 (MFMA gemm blocks)

    // CSR build (shared by all three convs)
    hipMemsetAsync(deg, 0, (size_t)NN * 4, stream);
    k_count<<<EB, 256, 0, stream>>>(ei, deg);
    k_part<<<NB, 256, 0, stream>>>(deg, part);
    k_scanp<<<1, 512, 0, stream>>>(part, NB);
    k_scan<<<NB, 256, 0, stream>>>(deg, part, rs, cur);
    k_scatter<<<EB, 256, 0, stream>>>(ei, cur, csr);

    // layer 1: two MFMA GEMMs into separate plain fp16 arrays
    gemm_mfma<128, 128, 1, true><<<GB, 256, 0, stream>>>(x_ppi, W1, xp_p, NN, 0);
    gemm_mfma<128, 128, 1, true><<<GB, 256, 0, stream>>>(x_go, W1, xp_g, NN, 0);
    attn1_plain<<<(NN * 4 + 255) / 256, 256, 0, stream>>>((const __half2*)xp_p, (const __half2*)xp_g,
                                                          as1, ad1, attsp, attdp, attsg, attdg, NN);
    w1prep_node<<<(NN + 15) / 16, 256, 0, stream>>>(rs, csr, (const float4*)attsp, (const float4*)attdp,
                                                    (const float4*)attsg, (const float4*)attdg,
                                                    (float4*)wbp, (float4*)wbg);
    // two working-set-split edge passes
    conv1_pass<<<NN / 4, 256, 0, stream>>>(rs, csr, (const uint4*)xp_p, wbp, b1, hbuf, 0);
    conv1_pass<<<NN / 4, 256, 0, stream>>>(rs, csr, (const uint4*)xp_g, wbg, b1, hbuf, 128);

    // layer 2
    gemm_mfma<256, 64, 1, false><<<GB, 256, 0, stream>>>(hbuf, W2, xp2, NN, 0);
    attn2_kernel<<<(NN + 255) / 256, 256, 0, stream>>>((const __half2*)xp2, as2, ad2, asr2, ads2, NN);
    conv2_edge<<<NN / 4, 256, 0, stream>>>(rs, csr, xp2, asr2, ads2, b2, out);
}

// Round 6
// 615.361 us; speedup vs baseline: 1.1272x; 1.1272x over previous
//
#include <hip/hip_runtime.h>
#include <hip/hip_fp16.h>

// Problem constants (fixed by the reference)
constexpr int NN = 100000;          // nodes
constexpr int EE = 1600000;         // edges (without self loops)
constexpr int ET = EE + NN;         // edges + self loops
constexpr int EQ = EE / 4;          // 400000 int4 groups of real edges
constexpr int TQ = ET / 4;          // 425000 int4 groups total (ET % 4 == 0)
constexpr float NEG = 0.2f;

typedef _Float16 f16x8 __attribute__((ext_vector_type(8)));
typedef _Float16 f16x4 __attribute__((ext_vector_type(4)));
typedef float    f32x4 __attribute__((ext_vector_type(4)));

// ---------------------------------------------------------------------------
// CSR build, rank-based (no scatter atomic):
//   k_count4: deg histogram via 4 independent atomics/thread; the returned
//             per-edge rank is stored COALESCED (int4).
//   scan    : rs = exclusive prefix of deg.
//   k_place4: pos = rs[dst] + rank  (no atomic; 4 independent chains/thread).
// ---------------------------------------------------------------------------
__global__ __launch_bounds__(256) void k_count4(const int4* __restrict__ dst4v, int* __restrict__ deg,
                                                int4* __restrict__ rank4) {
    int t = blockIdx.x * 256 + threadIdx.x;
    if (t >= TQ) return;
    int4 d;
    if (t < EQ) {
        d = dst4v[t];
    } else {
        int s0 = (t - EQ) * 4;             // self loops: dst = node id
        d.x = s0; d.y = s0 + 1; d.z = s0 + 2; d.w = s0 + 3;
    }
    int4 r;
    r.x = atomicAdd(&deg[d.x], 1);
    r.y = atomicAdd(&deg[d.y], 1);
    r.z = atomicAdd(&deg[d.z], 1);
    r.w = atomicAdd(&deg[d.w], 1);
    rank4[t] = r;
}

__global__ __launch_bounds__(256) void k_part(const int* __restrict__ deg, int* __restrict__ part) {
    __shared__ int sh[256];
    int i = blockIdx.x * 256 + threadIdx.x;
    sh[threadIdx.x] = (i < NN) ? deg[i] : 0;
    __syncthreads();
    for (int o = 128; o; o >>= 1) {
        if (threadIdx.x < o) sh[threadIdx.x] += sh[threadIdx.x + o];
        __syncthreads();
    }
    if (threadIdx.x == 0) part[blockIdx.x] = sh[0];
}

__global__ __launch_bounds__(512) void k_scanp(int* __restrict__ part, int nb) {
    __shared__ int sh[512];
    int t = threadIdx.x;
    int v = (t < nb) ? part[t] : 0;
    sh[t] = v;
    __syncthreads();
    for (int o = 1; o < 512; o <<= 1) {
        int u = (t >= o) ? sh[t - o] : 0;
        __syncthreads();
        sh[t] += u;
        __syncthreads();
    }
    if (t < nb) part[t] = sh[t] - v;   // exclusive
}

__global__ __launch_bounds__(256) void k_scan(const int* __restrict__ deg, const int* __restrict__ part,
                                              int* __restrict__ rs) {
    __shared__ int sh[256];
    int t = threadIdx.x;
    int i = blockIdx.x * 256 + t;
    int v = (i < NN) ? deg[i] : 0;
    sh[t] = v;
    __syncthreads();
    for (int o = 1; o < 256; o <<= 1) {
        int u = (t >= o) ? sh[t - o] : 0;
        __syncthreads();
        sh[t] += u;
        __syncthreads();
    }
    int incl = sh[t];
    int base = part[blockIdx.x];
    if (i < NN) {
        rs[i] = base + incl - v;
        if (i == NN - 1) rs[NN] = base + incl;
    }
}

__global__ __launch_bounds__(256) void k_place4(const int4* __restrict__ src4v, const int4* __restrict__ dst4v,
                                                const int4* __restrict__ rank4, const int* __restrict__ rs,
                                                int* __restrict__ csr) {
    int t = blockIdx.x * 256 + threadIdx.x;
    if (t >= TQ) return;
    int4 s, d;
    if (t < EQ) {
        s = src4v[t];
        d = dst4v[t];
    } else {
        int s0 = (t - EQ) * 4;             // self loops: src = dst = node id
        s.x = s0; s.y = s0 + 1; s.z = s0 + 2; s.w = s0 + 3;
        d = s;
    }
    int4 r = rank4[t];
    int p0 = rs[d.x] + r.x;
    int p1 = rs[d.y] + r.y;
    int p2 = rs[d.z] + r.z;
    int p3 = rs[d.w] + r.w;
    csr[p0] = s.x;
    csr[p1] = s.y;
    csr[p2] = s.z;
    csr[p3] = s.w;
}

// ---------------------------------------------------------------------------
// MFMA GEMM: xp = x @ W (fp16 inputs to matrix core, fp32 accumulate).
// OUT_MODE 1: plain fp16 row of C halves.
// ---------------------------------------------------------------------------
template <int K, int C, int OUT_MODE, bool SRCF32>
__global__ __launch_bounds__(256) void gemm_mfma(const void* __restrict__ xv, const float* __restrict__ W,
                                                 __half* __restrict__ xp, int n, int set_off) {
    constexpr int KC  = 64;          // K-chunk per stage
    constexpr int AST = KC + 8;      // padded LDS stride (halves)
    constexpr int NT  = C / 16;      // 16-col tiles
    constexpr int NST = K / KC;      // stages
    __shared__ _Float16 a_lds[128 * AST];
    __shared__ _Float16 w_lds[C * AST];

    const int tid  = threadIdx.x;
    const int w    = tid >> 6;
    const int lane = tid & 63;
    const int quad = lane >> 4;
    const int l16  = lane & 15;
    const long r0  = (long)blockIdx.x * 128;

    f32x4 acc[2][NT];
#pragma unroll
    for (int s = 0; s < 2; s++)
#pragma unroll
        for (int t = 0; t < NT; t++) acc[s][t] = (f32x4){0.f, 0.f, 0.f, 0.f};

    for (int st = 0; st < NST; ++st) {
        const int k0 = st * KC;
        // stage A: 128 rows x KC halves (convert fp32->fp16 if needed)
        for (int i = tid; i < 128 * (KC / 4); i += 256) {
            int r = i / (KC / 4);
            int q = i % (KC / 4);
            long row = r0 + r;
            f16x4 hv = (f16x4){0, 0, 0, 0};
            if (row < n) {
                if (SRCF32) {
                    float4 v = ((const float4*)xv)[row * (K / 4) + (k0 / 4) + q];
                    hv = (f16x4){(_Float16)v.x, (_Float16)v.y, (_Float16)v.z, (_Float16)v.w};
                } else {
                    hv = ((const f16x4*)xv)[row * (K / 4) + (k0 / 4) + q];
                }
            }
            *(f16x4*)&a_lds[r * AST + q * 4] = hv;
        }
        // stage W^T: w_lds[n][k] from W[k][n] (coalesced global reads over n)
        for (int i = tid; i < C * (KC / 4); i += 256) {
            int nn = i / (KC / 4);
            int kq = i % (KC / 4);
            f16x4 hv;
            hv.x = (_Float16)W[(long)(k0 + kq * 4 + 0) * C + nn];
            hv.y = (_Float16)W[(long)(k0 + kq * 4 + 1) * C + nn];
            hv.z = (_Float16)W[(long)(k0 + kq * 4 + 2) * C + nn];
            hv.w = (_Float16)W[(long)(k0 + kq * 4 + 3) * C + nn];
            *(f16x4*)&w_lds[nn * AST + kq * 4] = hv;
        }
        __syncthreads();

#pragma unroll
        for (int ks = 0; ks < KC; ks += 32) {
            f16x8 a0 = *(const f16x8*)&a_lds[(w * 32 + l16) * AST + ks + quad * 8];
            f16x8 a1 = *(const f16x8*)&a_lds[(w * 32 + 16 + l16) * AST + ks + quad * 8];
#pragma unroll
            for (int t = 0; t < NT; t++) {
                f16x8 b = *(const f16x8*)&w_lds[(t * 16 + l16) * AST + ks + quad * 8];
                acc[0][t] = __builtin_amdgcn_mfma_f32_16x16x32_f16(a0, b, acc[0][t], 0, 0, 0);
                acc[1][t] = __builtin_amdgcn_mfma_f32_16x16x32_f16(a1, b, acc[1][t], 0, 0, 0);
            }
        }
        __syncthreads();
    }

    // epilogue: C/D layout col=l16, row=quad*4+reg
#pragma unroll
    for (int sub = 0; sub < 2; sub++) {
        long rb = r0 + w * 32 + sub * 16 + quad * 4;
#pragma unroll
        for (int t = 0; t < NT; t++) {
            int c = t * 16 + l16;
#pragma unroll
            for (int rg = 0; rg < 4; rg++) {
                long row = rb + rg;
                if (row < n) {
                    __half hv = __float2half(acc[sub][t][rg]);
                    if (OUT_MODE == 0)
                        xp[row * 256 + ((c >> 1) << 2) + (c & 1) + set_off] = hv;
                    else
                        xp[row * (long)C + c] = hv;
                }
            }
        }
    }
}

// ---------------------------------------------------------------------------
// Attention coefficients for conv1 from the two plain fp16 feature arrays.
// Thread per (v, head). att_sp[v*4+h] = <xp_p[v], as1[h]>, etc.
// ---------------------------------------------------------------------------
__global__ __launch_bounds__(256) void attn1_plain(const __half2* __restrict__ xp_p,
                                                   const __half2* __restrict__ xp_g,
                                                   const float* __restrict__ as_w, const float* __restrict__ ad_w,
                                                   float* __restrict__ att_sp, float* __restrict__ att_dp,
                                                   float* __restrict__ att_sg, float* __restrict__ att_dg, int n) {
    int idx = blockIdx.x * 256 + threadIdx.x;
    if (idx >= n * 4) return;
    int v = idx >> 2, hh = idx & 3;
    const __half2* rp = xp_p + (long)v * 64 + hh * 16;
    const __half2* rg = xp_g + (long)v * 64 + hh * 16;
    const float* a1 = as_w + hh * 32;
    const float* a2 = ad_w + hh * 32;
    float sp1 = 0.f, sp2 = 0.f, sg1 = 0.f, sg2 = 0.f;
#pragma unroll
    for (int t = 0; t < 16; t++) {
        float2 fp = __half22float2(rp[t]);
        float2 fg = __half22float2(rg[t]);
        float2 w1 = *(const float2*)(a1 + 2 * t);
        float2 w2 = *(const float2*)(a2 + 2 * t);
        sp1 += fp.x * w1.x + fp.y * w1.y;
        sp2 += fp.x * w2.x + fp.y * w2.y;
        sg1 += fg.x * w1.x + fg.y * w1.y;
        sg2 += fg.x * w2.x + fg.y * w2.y;
    }
    att_sp[idx] = sp1; att_dp[idx] = sp2;
    att_sg[idx] = sg1; att_dg[idx] = sg2;
}

// attention for conv2 (H=1, C=64), fp16 xp
__global__ __launch_bounds__(256) void attn2_kernel(const __half2* __restrict__ xp,
                                                    const float* __restrict__ as_w, const float* __restrict__ ad_w,
                                                    float* __restrict__ asrc, float* __restrict__ adst, int n) {
    int v = blockIdx.x * 256 + threadIdx.x;
    if (v >= n) return;
    const __half2* p = xp + (long)v * 32;
    float s1 = 0.f, s2 = 0.f;
#pragma unroll
    for (int c = 0; c < 32; c++) {
        float2 xv = __half22float2(p[c]);
        float2 w1 = *(const float2*)(as_w + 2 * c);
        float2 w2 = *(const float2*)(ad_w + 2 * c);
        s1 += xv.x * w1.x + xv.y * w1.y;
        s2 += xv.x * w2.x + xv.y * w2.y;
    }
    asrc[v] = s1;
    adst[v] = s2;
}

// ---------------------------------------------------------------------------
// Per-edge exp-weights for conv1, CSR-ordered (no dstv needed): one 16-lane
// group per dst node. dst scores broadcast from att_d*[v]; src scores
// gathered from the L2-resident 1.6MB tables; csr reads + wb writes
// sequential/coalesced. Writes wb_p[j][4] and wb_g[j][4] (16B/edge each).
// ---------------------------------------------------------------------------
__global__ __launch_bounds__(256) void w1prep_node(const int* __restrict__ rs, const int* __restrict__ csr,
                                                   const float4* __restrict__ att_sp4, const float4* __restrict__ att_dp4,
                                                   const float4* __restrict__ att_sg4, const float4* __restrict__ att_dg4,
                                                   float4* __restrict__ wbp4, float4* __restrict__ wbg4) {
    int v = blockIdx.x * 16 + (threadIdx.x >> 4);
    if (v >= NN) return;
    int sl = threadIdx.x & 15;
    int e0 = rs[v], e1 = rs[v + 1];
    float4 dp = att_dp4[v], dg = att_dg4[v];
    auto w = [](float e) { e = (e > 0.f) ? e : NEG * e; return __expf(e); };
    for (int j = e0 + sl; j < e1; j += 16) {
        int s = csr[j];
        float4 sp = att_sp4[s], sg = att_sg4[s];
        float4 wp, wg;
        wp.x = w(sp.x + dp.x); wp.y = w(sp.y + dp.y);
        wp.z = w(sp.z + dp.z); wp.w = w(sp.w + dp.w);
        wg.x = w(sg.x + dg.x); wg.y = w(sg.y + dg.y);
        wg.z = w(sg.z + dg.z); wg.w = w(sg.w + dg.w);
        wbp4[j] = wp;
        wbg4[j] = wg;
    }
}

// ---------------------------------------------------------------------------
// conv1 single-set pass. Working-set split: this pass reads ONE 25.6MB
// feature array (256B rows) so L2 re-reference distance halves vs a packed
// 51MB layout -> higher hit rate -> fewer counted bytes. One wave per dst
// node; quarter-wave qw handles edges j+4k+qw; lane m (0..15) gathers 16B =
// channels 8m..8m+7. Weights streamed (4B/lane/edge). 16-edge full chunks
// (4 gathers in flight), 4-edge clamped tail. Combine via shfl_xor(16,32);
// qw==0 lanes write uint4 of 8 fp16 (bias+ReLU) into hbuf[v*256 + off + 8m].
// ---------------------------------------------------------------------------
__global__ __launch_bounds__(256) void conv1_pass(const int* __restrict__ rs, const int* __restrict__ csr,
                                                  const uint4* __restrict__ xp,
                                                  const float* __restrict__ wb,
                                                  const float* __restrict__ bias,
                                                  __half* __restrict__ out, int off) {
    int v = blockIdx.x * 4 + (threadIdx.x >> 6);
    if (v >= NN) return;
    int lane = threadIdx.x & 63;
    int qw = lane >> 4;                // quarter-wave: edge offset
    int m = lane & 15;                 // channels 8m..8m+7
    int hd = m >> 2;                   // head index for this lane's channels
    int e0 = rs[v], e1 = rs[v + 1];

    float a[8];
#pragma unroll
    for (int i = 0; i < 8; i++) a[i] = 0.f;
    float d = 0.f;

    int j = e0;
    // full chunks: 16 edges, 4 gathers in flight, no predication
    for (; j + 16 <= e1; j += 16) {
        int s[4]; float w[4]; uint4 r[4];
#pragma unroll
        for (int k = 0; k < 4; k++) s[k] = csr[j + 4 * k + qw];
#pragma unroll
        for (int k = 0; k < 4; k++) w[k] = wb[(j + 4 * k + qw) * 4 + hd];
#pragma unroll
        for (int k = 0; k < 4; k++) r[k] = xp[(long)s[k] * 16 + m];
#pragma unroll
        for (int k = 0; k < 4; k++) {
            d += w[k];
            float2 f0 = __half22float2(*(__half2*)&r[k].x);
            float2 f1 = __half22float2(*(__half2*)&r[k].y);
            float2 f2 = __half22float2(*(__half2*)&r[k].z);
            float2 f3 = __half22float2(*(__half2*)&r[k].w);
            a[0] += w[k] * f0.x; a[1] += w[k] * f0.y;
            a[2] += w[k] * f1.x; a[3] += w[k] * f1.y;
            a[4] += w[k] * f2.x; a[5] += w[k] * f2.y;
            a[6] += w[k] * f3.x; a[7] += w[k] * f3.y;
        }
    }
    // tail: 4 edges per iteration, clamped duplicate gathers with zero weight
    for (; j < e1; j += 4) {
        int jj = j + qw;
        int jc = (jj < e1) ? jj : (e1 - 1);
        int s = csr[jc];
        float w = (jj < e1) ? wb[jc * 4 + hd] : 0.f;
        uint4 r = xp[(long)s * 16 + m];
        d += w;
        float2 f0 = __half22float2(*(__half2*)&r.x);
        float2 f1 = __half22float2(*(__half2*)&r.y);
        float2 f2 = __half22float2(*(__half2*)&r.z);
        float2 f3 = __half22float2(*(__half2*)&r.w);
        a[0] += w * f0.x; a[1] += w * f0.y;
        a[2] += w * f1.x; a[3] += w * f1.y;
        a[4] += w * f2.x; a[5] += w * f2.y;
        a[6] += w * f3.x; a[7] += w * f3.y;
    }

    // combine the four quarters (disjoint edge subsets)
#pragma unroll
    for (int i = 0; i < 8; i++) {
        a[i] += __shfl_xor(a[i], 16);
        a[i] += __shfl_xor(a[i], 32);
    }
    d += __shfl_xor(d, 16);
    d += __shfl_xor(d, 32);

    if (qw == 0) {
        float inv = 1.0f / d;
        const float4* b4 = (const float4*)bias;
        float4 bA = b4[2 * m], bB = b4[2 * m + 1];
        __half2 o01 = __floats2half2_rn(fmaxf(a[0] * inv + bA.x, 0.f), fmaxf(a[1] * inv + bA.y, 0.f));
        __half2 o23 = __floats2half2_rn(fmaxf(a[2] * inv + bA.z, 0.f), fmaxf(a[3] * inv + bA.w, 0.f));
        __half2 o45 = __floats2half2_rn(fmaxf(a[4] * inv + bB.x, 0.f), fmaxf(a[5] * inv + bB.y, 0.f));
        __half2 o67 = __floats2half2_rn(fmaxf(a[6] * inv + bB.z, 0.f), fmaxf(a[7] * inv + bB.w, 0.f));
        uint4 st;
        st.x = *(unsigned int*)&o01;
        st.y = *(unsigned int*)&o23;
        st.z = *(unsigned int*)&o45;
        st.w = *(unsigned int*)&o67;
        *(uint4*)(out + (long)v * 256 + off + 8 * m) = st;
    }
}

// ---------------------------------------------------------------------------
// Single-pass conv2 edge kernel (H=1, C=64, fp16 xp). Weight inline from
// asrc[s] (400KB) + adst[v] register. Quarter-waves; 16-edge full chunks.
// ---------------------------------------------------------------------------
__global__ __launch_bounds__(256) void conv2_edge(const int* __restrict__ rs, const int* __restrict__ csr,
                                                  const __half* __restrict__ xp,
                                                  const float* __restrict__ asrc,
                                                  const float* __restrict__ adst,
                                                  const float* __restrict__ bias,
                                                  float* __restrict__ out) {
    int v = blockIdx.x * 4 + (threadIdx.x >> 6);
    if (v >= NN) return;
    int lane = threadIdx.x & 63;
    int qw = lane >> 4;                // quarter-wave: edge offset
    int m = lane & 15;                 // channels 4m..4m+3
    int e0 = rs[v], e1 = rs[v + 1];
    const uint2* xp2 = (const uint2*)xp;

    float adv = adst[v];
    auto lrexp = [](float e) { e = (e > 0.f) ? e : NEG * e; return __expf(e); };

    float a0 = 0.f, a1 = 0.f, a2 = 0.f, a3 = 0.f, d = 0.f;

    int j = e0;
    // full chunks: 16 edges, 4 gathers in flight, no predication
    for (; j + 16 <= e1; j += 16) {
        int s[4]; float av[4]; uint2 r[4];
#pragma unroll
        for (int k = 0; k < 4; k++) s[k] = csr[j + 4 * k + qw];
#pragma unroll
        for (int k = 0; k < 4; k++) av[k] = asrc[s[k]];
#pragma unroll
        for (int k = 0; k < 4; k++) r[k] = xp2[(long)s[k] * 16 + m];
#pragma unroll
        for (int k = 0; k < 4; k++) {
            float w = lrexp(av[k] + adv);
            d += w;
            float2 x01 = __half22float2(*(__half2*)&r[k].x);
            float2 x23 = __half22float2(*(__half2*)&r[k].y);
            a0 += w * x01.x; a1 += w * x01.y;
            a2 += w * x23.x; a3 += w * x23.y;
        }
    }
    // tail: 4 edges per iteration, clamped
    for (; j < e1; j += 4) {
        int jj = j + qw;
        int jc = (jj < e1) ? jj : (e1 - 1);
        int s = csr[jc];
        float av = asrc[s];
        uint2 r = xp2[(long)s * 16 + m];
        float w = (jj < e1) ? lrexp(av + adv) : 0.f;
        d += w;
        float2 x01 = __half22float2(*(__half2*)&r.x);
        float2 x23 = __half22float2(*(__half2*)&r.y);
        a0 += w * x01.x; a1 += w * x01.y;
        a2 += w * x23.x; a3 += w * x23.y;
    }

    // combine the four quarters
    a0 += __shfl_xor(a0, 16); a1 += __shfl_xor(a1, 16);
    a2 += __shfl_xor(a2, 16); a3 += __shfl_xor(a3, 16);
    d  += __shfl_xor(d, 16);
    a0 += __shfl_xor(a0, 32); a1 += __shfl_xor(a1, 32);
    a2 += __shfl_xor(a2, 32); a3 += __shfl_xor(a3, 32);
    d  += __shfl_xor(d, 32);

    if (qw == 0) {
        float inv = 1.0f / d;
        float4 b4 = *(const float4*)&bias[4 * m];
        float4 o;
        o.x = a0 * inv + b4.x;
        o.y = a1 * inv + b4.y;
        o.z = a2 * inv + b4.z;
        o.w = a3 * inv + b4.w;
        *(float4*)&out[(long)v * 64 + 4 * m] = o;
    }
}

// ---------------------------------------------------------------------------
// Launch
// ---------------------------------------------------------------------------
extern "C" void kernel_launch(void* const* d_in, const int* in_sizes, int n_in,
                              void* d_out, int out_size, void* d_ws, size_t ws_size,
                              hipStream_t stream) {
    const float* x_ppi = (const float*)d_in[0];
    const float* x_go  = (const float*)d_in[1];
    const int*   ei    = (const int*)d_in[2];
    const float* W1    = (const float*)d_in[3];
    const float* as1   = (const float*)d_in[4];
    const float* ad1   = (const float*)d_in[5];
    const float* b1    = (const float*)d_in[6];
    const float* W2    = (const float*)d_in[7];
    const float* as2   = (const float*)d_in[8];
    const float* ad2   = (const float*)d_in[9];
    const float* b2    = (const float*)d_in[10];
    float* out = (float*)d_out;

    char* ws = (char*)d_ws;
    size_t off = 0;
    auto alloc = [&](size_t bytes) -> void* {
        void* p = ws + off;
        off = (off + bytes + 255) & ~(size_t)255;
        return p;
    };
    int* deg     = (int*)alloc((size_t)NN * 4);
    int* rs      = (int*)alloc((size_t)(NN + 1) * 4);
    int* part    = (int*)alloc(512 * 4);
    int* csr     = (int*)alloc((size_t)ET * 4);
    int* rank    = (int*)alloc((size_t)ET * 4);
    __half* xp_p = (__half*)alloc((size_t)NN * 128 * 2);   // conv1 p-set features
    __half* xp_g = (__half*)alloc((size_t)NN * 128 * 2);   // conv1 g-set features
    __half* xp2  = (__half*)alloc((size_t)NN * 64 * 2);    // conv2 features fp16
    float* attsp = (float*)alloc((size_t)NN * 4 * 4);
    float* attdp = (float*)alloc((size_t)NN * 4 * 4);
    float* attsg = (float*)alloc((size_t)NN * 4 * 4);
    float* attdg = (float*)alloc((size_t)NN * 4 * 4);
    float* asr2  = (float*)alloc((size_t)NN * 4);
    float* ads2  = (float*)alloc((size_t)NN * 4);
    float* wbp   = (float*)alloc((size_t)ET * 16);         // 4 fp32 weights/edge (p)
    float* wbg   = (float*)alloc((size_t)ET * 16);         // 4 fp32 weights/edge (g)
    __half* hbuf = (__half*)alloc((size_t)NN * 256 * 2);   // conv1 output, fp16
    (void)ws_size; (void)in_sizes; (void)n_in; (void)out_size;

    const int NB = (NN + 255) / 256;        // 391
    const int QB = (TQ + 255) / 256;        // 1661 (int4 edge groups)
    const int GB = (NN + 127) / 128;        // 782 (MFMA gemm blocks)

    // CSR build, rank-based
    hipMemsetAsync(deg, 0, (size_t)NN * 4, stream);
    k_count4<<<QB, 256, 0, stream>>>((const int4*)(ei + EE), deg, (int4*)rank);
    k_part<<<NB, 256, 0, stream>>>(deg, part);
    k_scanp<<<1, 512, 0, stream>>>(part, NB);
    k_scan<<<NB, 256, 0, stream>>>(deg, part, rs);
    k_place4<<<QB, 256, 0, stream>>>((const int4*)ei, (const int4*)(ei + EE), (const int4*)rank, rs, csr);

    // layer 1: two MFMA GEMMs into separate plain fp16 arrays
    gemm_mfma<128, 128, 1, true><<<GB, 256, 0, stream>>>(x_ppi, W1, xp_p, NN, 0);
    gemm_mfma<128, 128, 1, true><<<GB, 256, 0, stream>>>(x_go, W1, xp_g, NN, 0);
    attn1_plain<<<(NN * 4 + 255) / 256, 256, 0, stream>>>((const __half2*)xp_p, (const __half2*)xp_g,
                                                          as1, ad1, attsp, attdp, attsg, attdg, NN);
    w1prep_node<<<(NN + 15) / 16, 256, 0, stream>>>(rs, csr, (const float4*)attsp, (const float4*)attdp,
                                                    (const float4*)attsg, (const float4*)attdg,
                                                    (float4*)wbp, (float4*)wbg);
    // two working-set-split edge passes
    conv1_pass<<<NN / 4, 256, 0, stream>>>(rs, csr, (const uint4*)xp_p, wbp, b1, hbuf, 0);
    conv1_pass<<<NN / 4, 256, 0, stream>>>(rs, csr, (const uint4*)xp_g, wbg, b1, hbuf, 128);

    // layer 2
    gemm_mfma<256, 64, 1, false><<<GB, 256, 0, stream>>>(hbuf, W2, xp2, NN, 0);
    attn2_kernel<<<(NN + 255) / 256, 256, 0, stream>>>((const __half2*)xp2, as2, ad2, asr2, ads2, NN);
    conv2_edge<<<NN / 4, 256, 0, stream>>>(rs, csr, xp2, asr2, ads2, b2, out);
}

// Round 7
// 562.957 us; speedup vs baseline: 1.2321x; 1.0931x over previous
//
#include <hip/hip_runtime.h>
#include <hip/hip_fp16.h>

// Problem constants (fixed by the reference)
constexpr int NN = 100000;          // nodes
constexpr int EE = 1600000;         // edges (without self loops)
constexpr int ET = EE + NN;         // edges + self loops
constexpr int EQ = EE / 4;          // 400000 int4 groups of real edges
constexpr int TQ = ET / 4;          // 425000 int4 groups total (ET % 4 == 0)
constexpr int NBUK = (NN + 255) / 256;  // 391 dst-buckets of 256 nodes
constexpr int PB = 416;             // blocks for bucket count/place (416*256*4 >= TQ)
constexpr float NEG = 0.2f;

typedef _Float16 f16x8 __attribute__((ext_vector_type(8)));
typedef _Float16 f16x4 __attribute__((ext_vector_type(4)));
typedef float    f32x4 __attribute__((ext_vector_type(4)));

// ---------------------------------------------------------------------------
// CSR build, two-level counting sort (bucket = dst>>8, 391 buckets):
//   k_bcount: LDS bucket histogram -> 1 global atomic per (block,bucket).
//   k_bscan : scan bucket counts -> bstart, gcur; writes rs[NN]=ET.
//   k_bplace: LDS local ranks + per-(block,bucket) base atomic; writes each
//             edge once, packed (ldst<<24)|src, into block-contiguous
//             sub-ranges of its bucket (L2 write-merge friendly).
//   k_csr   : one block per bucket; LDS histogram over 256 local dsts (LDS
//             atomics), LDS scan -> rs, then place -> csr.
// Global atomics: ~162K + 162K (vs 1.7M+1.7M for the flat build).
// ---------------------------------------------------------------------------
__global__ __launch_bounds__(256) void k_bcount(const int4* __restrict__ dst4v,
                                                int* __restrict__ bucketCount) {
    __shared__ int bh[NBUK];
    for (int i = threadIdx.x; i < NBUK; i += 256) bh[i] = 0;
    __syncthreads();
    int gtid = blockIdx.x * 256 + threadIdx.x;
    for (int q = gtid; q < TQ; q += PB * 256) {
        int4 d;
        if (q < EQ) {
            d = dst4v[q];
        } else {
            int s0 = (q - EQ) * 4;       // self loops: dst = node id
            d.x = s0; d.y = s0 + 1; d.z = s0 + 2; d.w = s0 + 3;
        }
        atomicAdd(&bh[d.x >> 8], 1);
        atomicAdd(&bh[d.y >> 8], 1);
        atomicAdd(&bh[d.z >> 8], 1);
        atomicAdd(&bh[d.w >> 8], 1);
    }
    __syncthreads();
    for (int i = threadIdx.x; i < NBUK; i += 256)
        if (bh[i]) atomicAdd(&bucketCount[i], bh[i]);
}

__global__ __launch_bounds__(512) void k_bscan(const int* __restrict__ bucketCount,
                                               int* __restrict__ bstart, int* __restrict__ gcur,
                                               int* __restrict__ rs) {
    __shared__ int sh[512];
    int t = threadIdx.x;
    int v = (t < NBUK) ? bucketCount[t] : 0;
    sh[t] = v;
    __syncthreads();
    for (int o = 1; o < 512; o <<= 1) {
        int u = (t >= o) ? sh[t - o] : 0;
        __syncthreads();
        sh[t] += u;
        __syncthreads();
    }
    if (t < NBUK) { bstart[t] = sh[t] - v; gcur[t] = sh[t] - v; }
    if (t == 0) { bstart[NBUK] = ET; rs[NN] = ET; }
}

__global__ __launch_bounds__(256) void k_bplace(const int4* __restrict__ src4v, const int4* __restrict__ dst4v,
                                                int* __restrict__ gcur, unsigned int* __restrict__ ebuf) {
    __shared__ int bh[NBUK];
    __shared__ int bbase[NBUK];
    for (int i = threadIdx.x; i < NBUK; i += 256) bh[i] = 0;
    __syncthreads();
    int gtid = blockIdx.x * 256 + threadIdx.x;

    int esrc[16];
    int emeta[16];   // (b<<21) | (ldst<<13) | lrank  (lrank < 4096+pad -> 13 bits)
#pragma unroll
    for (int it = 0; it < 4; it++) {
        int q = gtid + it * (PB * 256);
        bool valid = q < TQ;
        int4 s, d;
        if (valid) {
            if (q < EQ) { s = src4v[q]; d = dst4v[q]; }
            else { int s0 = (q - EQ) * 4; s.x = s0; s.y = s0 + 1; s.z = s0 + 2; s.w = s0 + 3; d = s; }
        } else {
            s.x = s.y = s.z = s.w = 0; d = s;
        }
        int ss[4] = {s.x, s.y, s.z, s.w};
        int dd[4] = {d.x, d.y, d.z, d.w};
#pragma unroll
        for (int k = 0; k < 4; k++) {
            int idx = it * 4 + k;
            if (valid) {
                int b = dd[k] >> 8, l = dd[k] & 255;
                int r = atomicAdd(&bh[b], 1);
                esrc[idx]  = ss[k];
                emeta[idx] = (b << 21) | (l << 13) | r;
            } else {
                emeta[idx] = -1;
            }
        }
    }
    __syncthreads();
    for (int i = threadIdx.x; i < NBUK; i += 256)
        bbase[i] = bh[i] ? atomicAdd(&gcur[i], bh[i]) : 0;
    __syncthreads();
#pragma unroll
    for (int e = 0; e < 16; e++) {
        int me = emeta[e];
        if (me >= 0) {
            int b = me >> 21, l = (me >> 13) & 255, r = me & 8191;
            ebuf[bbase[b] + r] = ((unsigned)l << 24) | (unsigned)esrc[e];
        }
    }
}

__global__ __launch_bounds__(256) void k_csr(const unsigned int* __restrict__ ebuf,
                                             const int* __restrict__ bstart,
                                             int* __restrict__ rs, int* __restrict__ csr) {
    __shared__ int hist[256];
    __shared__ int sh[256];
    __shared__ int cur[256];
    int b = blockIdx.x;
    int t = threadIdx.x;
    int e0 = bstart[b], e1 = bstart[b + 1];
    hist[t] = 0;
    __syncthreads();
    for (int j = e0 + t; j < e1; j += 256)
        atomicAdd(&hist[ebuf[j] >> 24], 1);
    __syncthreads();
    int v = hist[t];
    sh[t] = v;
    __syncthreads();
    for (int o = 1; o < 256; o <<= 1) {
        int u = (t >= o) ? sh[t - o] : 0;
        __syncthreads();
        sh[t] += u;
        __syncthreads();
    }
    int excl = sh[t] - v;
    cur[t] = excl;
    int v0 = b * 256;
    if (v0 + t < NN) rs[v0 + t] = e0 + excl;
    __syncthreads();
    for (int j = e0 + t; j < e1; j += 256) {
        unsigned int e = ebuf[j];
        int l = (int)(e >> 24);
        int r = atomicAdd(&cur[l], 1);
        csr[e0 + r] = (int)(e & 0x00FFFFFFu);
    }
}

// ---------------------------------------------------------------------------
// MFMA GEMM: xp = x @ W (fp16 inputs to matrix core, fp32 accumulate).
// OUT_MODE 1: plain fp16 row of C halves.
// ---------------------------------------------------------------------------
template <int K, int C, int OUT_MODE, bool SRCF32>
__global__ __launch_bounds__(256) void gemm_mfma(const void* __restrict__ xv, const float* __restrict__ W,
                                                 __half* __restrict__ xp, int n, int set_off) {
    constexpr int KC  = 64;          // K-chunk per stage
    constexpr int AST = KC + 8;      // padded LDS stride (halves)
    constexpr int NT  = C / 16;      // 16-col tiles
    constexpr int NST = K / KC;      // stages
    __shared__ _Float16 a_lds[128 * AST];
    __shared__ _Float16 w_lds[C * AST];

    const int tid  = threadIdx.x;
    const int w    = tid >> 6;
    const int lane = tid & 63;
    const int quad = lane >> 4;
    const int l16  = lane & 15;
    const long r0  = (long)blockIdx.x * 128;

    f32x4 acc[2][NT];
#pragma unroll
    for (int s = 0; s < 2; s++)
#pragma unroll
        for (int t = 0; t < NT; t++) acc[s][t] = (f32x4){0.f, 0.f, 0.f, 0.f};

    for (int st = 0; st < NST; ++st) {
        const int k0 = st * KC;
        // stage A: 128 rows x KC halves (convert fp32->fp16 if needed)
        for (int i = tid; i < 128 * (KC / 4); i += 256) {
            int r = i / (KC / 4);
            int q = i % (KC / 4);
            long row = r0 + r;
            f16x4 hv = (f16x4){0, 0, 0, 0};
            if (row < n) {
                if (SRCF32) {
                    float4 v = ((const float4*)xv)[row * (K / 4) + (k0 / 4) + q];
                    hv = (f16x4){(_Float16)v.x, (_Float16)v.y, (_Float16)v.z, (_Float16)v.w};
                } else {
                    hv = ((const f16x4*)xv)[row * (K / 4) + (k0 / 4) + q];
                }
            }
            *(f16x4*)&a_lds[r * AST + q * 4] = hv;
        }
        // stage W^T: w_lds[n][k] from W[k][n] (coalesced global reads over n)
        for (int i = tid; i < C * (KC / 4); i += 256) {
            int nn = i / (KC / 4);
            int kq = i % (KC / 4);
            f16x4 hv;
            hv.x = (_Float16)W[(long)(k0 + kq * 4 + 0) * C + nn];
            hv.y = (_Float16)W[(long)(k0 + kq * 4 + 1) * C + nn];
            hv.z = (_Float16)W[(long)(k0 + kq * 4 + 2) * C + nn];
            hv.w = (_Float16)W[(long)(k0 + kq * 4 + 3) * C + nn];
            *(f16x4*)&w_lds[nn * AST + kq * 4] = hv;
        }
        __syncthreads();

#pragma unroll
        for (int ks = 0; ks < KC; ks += 32) {
            f16x8 a0 = *(const f16x8*)&a_lds[(w * 32 + l16) * AST + ks + quad * 8];
            f16x8 a1 = *(const f16x8*)&a_lds[(w * 32 + 16 + l16) * AST + ks + quad * 8];
#pragma unroll
            for (int t = 0; t < NT; t++) {
                f16x8 b = *(const f16x8*)&w_lds[(t * 16 + l16) * AST + ks + quad * 8];
                acc[0][t] = __builtin_amdgcn_mfma_f32_16x16x32_f16(a0, b, acc[0][t], 0, 0, 0);
                acc[1][t] = __builtin_amdgcn_mfma_f32_16x16x32_f16(a1, b, acc[1][t], 0, 0, 0);
            }
        }
        __syncthreads();
    }

    // epilogue: C/D layout col=l16, row=quad*4+reg
#pragma unroll
    for (int sub = 0; sub < 2; sub++) {
        long rb = r0 + w * 32 + sub * 16 + quad * 4;
#pragma unroll
        for (int t = 0; t < NT; t++) {
            int c = t * 16 + l16;
#pragma unroll
            for (int rg = 0; rg < 4; rg++) {
                long row = rb + rg;
                if (row < n) {
                    __half hv = __float2half(acc[sub][t][rg]);
                    if (OUT_MODE == 0)
                        xp[row * 256 + ((c >> 1) << 2) + (c & 1) + set_off] = hv;
                    else
                        xp[row * (long)C + c] = hv;
                }
            }
        }
    }
}

// ---------------------------------------------------------------------------
// Attention coefficients for conv1 from the two plain fp16 feature arrays.
// Thread per (v, head). att_sp[v*4+h] = <xp_p[v], as1[h]>, etc.
// ---------------------------------------------------------------------------
__global__ __launch_bounds__(256) void attn1_plain(const __half2* __restrict__ xp_p,
                                                   const __half2* __restrict__ xp_g,
                                                   const float* __restrict__ as_w, const float* __restrict__ ad_w,
                                                   float* __restrict__ att_sp, float* __restrict__ att_dp,
                                                   float* __restrict__ att_sg, float* __restrict__ att_dg, int n) {
    int idx = blockIdx.x * 256 + threadIdx.x;
    if (idx >= n * 4) return;
    int v = idx >> 2, hh = idx & 3;
    const __half2* rp = xp_p + (long)v * 64 + hh * 16;
    const __half2* rg = xp_g + (long)v * 64 + hh * 16;
    const float* a1 = as_w + hh * 32;
    const float* a2 = ad_w + hh * 32;
    float sp1 = 0.f, sp2 = 0.f, sg1 = 0.f, sg2 = 0.f;
#pragma unroll
    for (int t = 0; t < 16; t++) {
        float2 fp = __half22float2(rp[t]);
        float2 fg = __half22float2(rg[t]);
        float2 w1 = *(const float2*)(a1 + 2 * t);
        float2 w2 = *(const float2*)(a2 + 2 * t);
        sp1 += fp.x * w1.x + fp.y * w1.y;
        sp2 += fp.x * w2.x + fp.y * w2.y;
        sg1 += fg.x * w1.x + fg.y * w1.y;
        sg2 += fg.x * w2.x + fg.y * w2.y;
    }
    att_sp[idx] = sp1; att_dp[idx] = sp2;
    att_sg[idx] = sg1; att_dg[idx] = sg2;
}

// attention for conv2 (H=1, C=64), fp16 xp
__global__ __launch_bounds__(256) void attn2_kernel(const __half2* __restrict__ xp,
                                                    const float* __restrict__ as_w, const float* __restrict__ ad_w,
                                                    float* __restrict__ asrc, float* __restrict__ adst, int n) {
    int v = blockIdx.x * 256 + threadIdx.x;
    if (v >= n) return;
    const __half2* p = xp + (long)v * 32;
    float s1 = 0.f, s2 = 0.f;
#pragma unroll
    for (int c = 0; c < 32; c++) {
        float2 xv = __half22float2(p[c]);
        float2 w1 = *(const float2*)(as_w + 2 * c);
        float2 w2 = *(const float2*)(ad_w + 2 * c);
        s1 += xv.x * w1.x + xv.y * w1.y;
        s2 += xv.x * w2.x + xv.y * w2.y;
    }
    asrc[v] = s1;
    adst[v] = s2;
}

// ---------------------------------------------------------------------------
// Per-edge exp-weights for conv1, CSR-ordered (no dstv needed): one 16-lane
// group per dst node. dst scores broadcast from att_d*[v]; src scores
// gathered from the L2-resident 1.6MB tables; csr reads + wb writes
// sequential/coalesced. Writes wb_p[j][4] and wb_g[j][4] (16B/edge each).
// ---------------------------------------------------------------------------
__global__ __launch_bounds__(256) void w1prep_node(const int* __restrict__ rs, const int* __restrict__ csr,
                                                   const float4* __restrict__ att_sp4, const float4* __restrict__ att_dp4,
                                                   const float4* __restrict__ att_sg4, const float4* __restrict__ att_dg4,
                                                   float4* __restrict__ wbp4, float4* __restrict__ wbg4) {
    int v = blockIdx.x * 16 + (threadIdx.x >> 4);
    if (v >= NN) return;
    int sl = threadIdx.x & 15;
    int e0 = rs[v], e1 = rs[v + 1];
    float4 dp = att_dp4[v], dg = att_dg4[v];
    auto w = [](float e) { e = (e > 0.f) ? e : NEG * e; return __expf(e); };
    for (int j = e0 + sl; j < e1; j += 16) {
        int s = csr[j];
        float4 sp = att_sp4[s], sg = att_sg4[s];
        float4 wp, wg;
        wp.x = w(sp.x + dp.x); wp.y = w(sp.y + dp.y);
        wp.z = w(sp.z + dp.z); wp.w = w(sp.w + dp.w);
        wg.x = w(sg.x + dg.x); wg.y = w(sg.y + dg.y);
        wg.z = w(sg.z + dg.z); wg.w = w(sg.w + dg.w);
        wbp4[j] = wp;
        wbg4[j] = wg;
    }
}

// ---------------------------------------------------------------------------
// conv1 single-set pass. Working-set split: this pass reads ONE 25.6MB
// feature array (256B rows) so L2 re-reference distance halves vs a packed
// 51MB layout -> higher hit rate -> fewer counted bytes. One wave per dst
// node; quarter-wave qw handles edges j+4k+qw; lane m (0..15) gathers 16B =
// channels 8m..8m+7. Weights streamed (4B/lane/edge). 16-edge full chunks
// (4 gathers in flight), 4-edge clamped tail. Combine via shfl_xor(16,32);
// qw==0 lanes write uint4 of 8 fp16 (bias+ReLU) into hbuf[v*256 + off + 8m].
// ---------------------------------------------------------------------------
__global__ __launch_bounds__(256) void conv1_pass(const int* __restrict__ rs, const int* __restrict__ csr,
                                                  const uint4* __restrict__ xp,
                                                  const float* __restrict__ wb,
                                                  const float* __restrict__ bias,
                                                  __half* __restrict__ out, int off) {
    int v = blockIdx.x * 4 + (threadIdx.x >> 6);
    if (v >= NN) return;
    int lane = threadIdx.x & 63;
    int qw = lane >> 4;                // quarter-wave: edge offset
    int m = lane & 15;                 // channels 8m..8m+7
    int hd = m >> 2;                   // head index for this lane's channels
    int e0 = rs[v], e1 = rs[v + 1];

    float a[8];
#pragma unroll
    for (int i = 0; i < 8; i++) a[i] = 0.f;
    float d = 0.f;

    int j = e0;
    // full chunks: 16 edges, 4 gathers in flight, no predication
    for (; j + 16 <= e1; j += 16) {
        int s[4]; float w[4]; uint4 r[4];
#pragma unroll
        for (int k = 0; k < 4; k++) s[k] = csr[j + 4 * k + qw];
#pragma unroll
        for (int k = 0; k < 4; k++) w[k] = wb[(j + 4 * k + qw) * 4 + hd];
#pragma unroll
        for (int k = 0; k < 4; k++) r[k] = xp[(long)s[k] * 16 + m];
#pragma unroll
        for (int k = 0; k < 4; k++) {
            d += w[k];
            float2 f0 = __half22float2(*(__half2*)&r[k].x);
            float2 f1 = __half22float2(*(__half2*)&r[k].y);
            float2 f2 = __half22float2(*(__half2*)&r[k].z);
            float2 f3 = __half22float2(*(__half2*)&r[k].w);
            a[0] += w[k] * f0.x; a[1] += w[k] * f0.y;
            a[2] += w[k] * f1.x; a[3] += w[k] * f1.y;
            a[4] += w[k] * f2.x; a[5] += w[k] * f2.y;
            a[6] += w[k] * f3.x; a[7] += w[k] * f3.y;
        }
    }
    // tail: 4 edges per iteration, clamped duplicate gathers with zero weight
    for (; j < e1; j += 4) {
        int jj = j + qw;
        int jc = (jj < e1) ? jj : (e1 - 1);
        int s = csr[jc];
        float w = (jj < e1) ? wb[jc * 4 + hd] : 0.f;
        uint4 r = xp[(long)s * 16 + m];
        d += w;
        float2 f0 = __half22float2(*(__half2*)&r.x);
        float2 f1 = __half22float2(*(__half2*)&r.y);
        float2 f2 = __half22float2(*(__half2*)&r.z);
        float2 f3 = __half22float2(*(__half2*)&r.w);
        a[0] += w * f0.x; a[1] += w * f0.y;
        a[2] += w * f1.x; a[3] += w * f1.y;
        a[4] += w * f2.x; a[5] += w * f2.y;
        a[6] += w * f3.x; a[7] += w * f3.y;
    }

    // combine the four quarters (disjoint edge subsets)
#pragma unroll
    for (int i = 0; i < 8; i++) {
        a[i] += __shfl_xor(a[i], 16);
        a[i] += __shfl_xor(a[i], 32);
    }
    d += __shfl_xor(d, 16);
    d += __shfl_xor(d, 32);

    if (qw == 0) {
        float inv = 1.0f / d;
        const float4* b4 = (const float4*)bias;
        float4 bA = b4[2 * m], bB = b4[2 * m + 1];
        __half2 o01 = __floats2half2_rn(fmaxf(a[0] * inv + bA.x, 0.f), fmaxf(a[1] * inv + bA.y, 0.f));
        __half2 o23 = __floats2half2_rn(fmaxf(a[2] * inv + bA.z, 0.f), fmaxf(a[3] * inv + bA.w, 0.f));
        __half2 o45 = __floats2half2_rn(fmaxf(a[4] * inv + bB.x, 0.f), fmaxf(a[5] * inv + bB.y, 0.f));
        __half2 o67 = __floats2half2_rn(fmaxf(a[6] * inv + bB.z, 0.f), fmaxf(a[7] * inv + bB.w, 0.f));
        uint4 st;
        st.x = *(unsigned int*)&o01;
        st.y = *(unsigned int*)&o23;
        st.z = *(unsigned int*)&o45;
        st.w = *(unsigned int*)&o67;
        *(uint4*)(out + (long)v * 256 + off + 8 * m) = st;
    }
}

// ---------------------------------------------------------------------------
// Single-pass conv2 edge kernel (H=1, C=64, fp16 xp). Weight inline from
// asrc[s] (400KB) + adst[v] register. Quarter-waves; 16-edge full chunks.
// ---------------------------------------------------------------------------
__global__ __launch_bounds__(256) void conv2_edge(const int* __restrict__ rs, const int* __restrict__ csr,
                                                  const __half* __restrict__ xp,
                                                  const float* __restrict__ asrc,
                                                  const float* __restrict__ adst,
                                                  const float* __restrict__ bias,
                                                  float* __restrict__ out) {
    int v = blockIdx.x * 4 + (threadIdx.x >> 6);
    if (v >= NN) return;
    int lane = threadIdx.x & 63;
    int qw = lane >> 4;                // quarter-wave: edge offset
    int m = lane & 15;                 // channels 4m..4m+3
    int e0 = rs[v], e1 = rs[v + 1];
    const uint2* xp2 = (const uint2*)xp;

    float adv = adst[v];
    auto lrexp = [](float e) { e = (e > 0.f) ? e : NEG * e; return __expf(e); };

    float a0 = 0.f, a1 = 0.f, a2 = 0.f, a3 = 0.f, d = 0.f;

    int j = e0;
    // full chunks: 16 edges, 4 gathers in flight, no predication
    for (; j + 16 <= e1; j += 16) {
        int s[4]; float av[4]; uint2 r[4];
#pragma unroll
        for (int k = 0; k < 4; k++) s[k] = csr[j + 4 * k + qw];
#pragma unroll
        for (int k = 0; k < 4; k++) av[k] = asrc[s[k]];
#pragma unroll
        for (int k = 0; k < 4; k++) r[k] = xp2[(long)s[k] * 16 + m];
#pragma unroll
        for (int k = 0; k < 4; k++) {
            float w = lrexp(av[k] + adv);
            d += w;
            float2 x01 = __half22float2(*(__half2*)&r[k].x);
            float2 x23 = __half22float2(*(__half2*)&r[k].y);
            a0 += w * x01.x; a1 += w * x01.y;
            a2 += w * x23.x; a3 += w * x23.y;
        }
    }
    // tail: 4 edges per iteration, clamped
    for (; j < e1; j += 4) {
        int jj = j + qw;
        int jc = (jj < e1) ? jj : (e1 - 1);
        int s = csr[jc];
        float av = asrc[s];
        uint2 r = xp2[(long)s * 16 + m];
        float w = (jj < e1) ? lrexp(av + adv) : 0.f;
        d += w;
        float2 x01 = __half22float2(*(__half2*)&r.x);
        float2 x23 = __half22float2(*(__half2*)&r.y);
        a0 += w * x01.x; a1 += w * x01.y;
        a2 += w * x23.x; a3 += w * x23.y;
    }

    // combine the four quarters
    a0 += __shfl_xor(a0, 16); a1 += __shfl_xor(a1, 16);
    a2 += __shfl_xor(a2, 16); a3 += __shfl_xor(a3, 16);
    d  += __shfl_xor(d, 16);
    a0 += __shfl_xor(a0, 32); a1 += __shfl_xor(a1, 32);
    a2 += __shfl_xor(a2, 32); a3 += __shfl_xor(a3, 32);
    d  += __shfl_xor(d, 32);

    if (qw == 0) {
        float inv = 1.0f / d;
        float4 b4 = *(const float4*)&bias[4 * m];
        float4 o;
        o.x = a0 * inv + b4.x;
        o.y = a1 * inv + b4.y;
        o.z = a2 * inv + b4.z;
        o.w = a3 * inv + b4.w;
        *(float4*)&out[(long)v * 64 + 4 * m] = o;
    }
}

// ---------------------------------------------------------------------------
// Launch
// ---------------------------------------------------------------------------
extern "C" void kernel_launch(void* const* d_in, const int* in_sizes, int n_in,
                              void* d_out, int out_size, void* d_ws, size_t ws_size,
                              hipStream_t stream) {
    const float* x_ppi = (const float*)d_in[0];
    const float* x_go  = (const float*)d_in[1];
    const int*   ei    = (const int*)d_in[2];
    const float* W1    = (const float*)d_in[3];
    const float* as1   = (const float*)d_in[4];
    const float* ad1   = (const float*)d_in[5];
    const float* b1    = (const float*)d_in[6];
    const float* W2    = (const float*)d_in[7];
    const float* as2   = (const float*)d_in[8];
    const float* ad2   = (const float*)d_in[9];
    const float* b2    = (const float*)d_in[10];
    float* out = (float*)d_out;

    char* ws = (char*)d_ws;
    size_t off = 0;
    auto alloc = [&](size_t bytes) -> void* {
        void* p = ws + off;
        off = (off + bytes + 255) & ~(size_t)255;
        return p;
    };
    int* bucketCount = (int*)alloc((size_t)NBUK * 4);
    int* bstart      = (int*)alloc((size_t)(NBUK + 1) * 4);
    int* gcur        = (int*)alloc((size_t)NBUK * 4);
    unsigned int* ebuf = (unsigned int*)alloc((size_t)ET * 4);
    int* rs      = (int*)alloc((size_t)(NN + 1) * 4);
    int* csr     = (int*)alloc((size_t)ET * 4);
    __half* xp_p = (__half*)alloc((size_t)NN * 128 * 2);   // conv1 p-set features
    __half* xp_g = (__half*)alloc((size_t)NN * 128 * 2);   // conv1 g-set features
    __half* xp2  = (__half*)alloc((size_t)NN * 64 * 2);    // conv2 features fp16
    float* attsp = (float*)alloc((size_t)NN * 4 * 4);
    float* attdp = (float*)alloc((size_t)NN * 4 * 4);
    float* attsg = (float*)alloc((size_t)NN * 4 * 4);
    float* attdg = (float*)alloc((size_t)NN * 4 * 4);
    float* asr2  = (float*)alloc((size_t)NN * 4);
    float* ads2  = (float*)alloc((size_t)NN * 4);
    float* wbp   = (float*)alloc((size_t)ET * 16);         // 4 fp32 weights/edge (p)
    float* wbg   = (float*)alloc((size_t)ET * 16);         // 4 fp32 weights/edge (g)
    __half* hbuf = (__half*)alloc((size_t)NN * 256 * 2);   // conv1 output, fp16
    (void)ws_size; (void)in_sizes; (void)n_in; (void)out_size;

    const int GB = (NN + 127) / 128;        // 782 (MFMA gemm blocks)

    // CSR build: two-level counting sort
    hipMemsetAsync(bucketCount, 0, (size_t)NBUK * 4, stream);
    k_bcount<<<PB, 256, 0, stream>>>((const int4*)(ei + EE), bucketCount);
    k_bscan<<<1, 512, 0, stream>>>(bucketCount, bstart, gcur, rs);
    k_bplace<<<PB, 256, 0, stream>>>((const int4*)ei, (const int4*)(ei + EE), gcur, ebuf);
    k_csr<<<NBUK, 256, 0, stream>>>(ebuf, bstart, rs, csr);

    // layer 1: two MFMA GEMMs into separate plain fp16 arrays
    gemm_mfma<128, 128, 1, true><<<GB, 256, 0, stream>>>(x_ppi, W1, xp_p, NN, 0);
    gemm_mfma<128, 128, 1, true><<<GB, 256, 0, stream>>>(x_go, W1, xp_g, NN, 0);
    attn1_plain<<<(NN * 4 + 255) / 256, 256, 0, stream>>>((const __half2*)xp_p, (const __half2*)xp_g,
                                                          as1, ad1, attsp, attdp, attsg, attdg, NN);
    w1prep_node<<<(NN + 15) / 16, 256, 0, stream>>>(rs, csr, (const float4*)attsp, (const float4*)attdp,
                                                    (const float4*)attsg, (const float4*)attdg,
                                                    (float4*)wbp, (float4*)wbg);
    // two working-set-split edge passes
    conv1_pass<<<NN / 4, 256, 0, stream>>>(rs, csr, (const uint4*)xp_p, wbp, b1, hbuf, 0);
    conv1_pass<<<NN / 4, 256, 0, stream>>>(rs, csr, (const uint4*)xp_g, wbg, b1, hbuf, 128);

    // layer 2
    gemm_mfma<256, 64, 1, false><<<GB, 256, 0, stream>>>(hbuf, W2, xp2, NN, 0);
    attn2_kernel<<<(NN + 255) / 256, 256, 0, stream>>>((const __half2*)xp2, as2, ad2, asr2, ads2, NN);
    conv2_edge<<<NN / 4, 256, 0, stream>>>(rs, csr, xp2, asr2, ads2, b2, out);
}

// Round 8
// 505.700 us; speedup vs baseline: 1.3716x; 1.1132x over previous
//
#include <hip/hip_runtime.h>
#include <hip/hip_fp16.h>

// Problem constants (fixed by the reference)
constexpr int NN = 100000;          // nodes
constexpr int EE = 1600000;         // edges (without self loops)
constexpr int ET = EE + NN;         // edges + self loops
constexpr int EQ = EE / 4;          // 400000 int4 groups of real edges
constexpr int TQ = ET / 4;          // 425000 int4 groups total (ET % 4 == 0)
constexpr int NBUK = (NN + 255) / 256;  // 391 dst-buckets of 256 nodes
constexpr int PB = 416;             // blocks for bucket count/place (416*256*4 >= TQ)
constexpr float NEG = 0.2f;

typedef _Float16 f16x8 __attribute__((ext_vector_type(8)));
typedef _Float16 f16x4 __attribute__((ext_vector_type(4)));
typedef float    f32x4 __attribute__((ext_vector_type(4)));

// ---------------------------------------------------------------------------
// CSR build, two-level counting sort (bucket = dst>>8, 391 buckets).
// ---------------------------------------------------------------------------
__global__ __launch_bounds__(256) void k_bcount(const int4* __restrict__ dst4v,
                                                int* __restrict__ bucketCount) {
    __shared__ int bh[NBUK];
    for (int i = threadIdx.x; i < NBUK; i += 256) bh[i] = 0;
    __syncthreads();
    int gtid = blockIdx.x * 256 + threadIdx.x;
    for (int q = gtid; q < TQ; q += PB * 256) {
        int4 d;
        if (q < EQ) {
            d = dst4v[q];
        } else {
            int s0 = (q - EQ) * 4;       // self loops: dst = node id
            d.x = s0; d.y = s0 + 1; d.z = s0 + 2; d.w = s0 + 3;
        }
        atomicAdd(&bh[d.x >> 8], 1);
        atomicAdd(&bh[d.y >> 8], 1);
        atomicAdd(&bh[d.z >> 8], 1);
        atomicAdd(&bh[d.w >> 8], 1);
    }
    __syncthreads();
    for (int i = threadIdx.x; i < NBUK; i += 256)
        if (bh[i]) atomicAdd(&bucketCount[i], bh[i]);
}

__global__ __launch_bounds__(512) void k_bscan(const int* __restrict__ bucketCount,
                                               int* __restrict__ bstart, int* __restrict__ gcur,
                                               int* __restrict__ rs) {
    __shared__ int sh[512];
    int t = threadIdx.x;
    int v = (t < NBUK) ? bucketCount[t] : 0;
    sh[t] = v;
    __syncthreads();
    for (int o = 1; o < 512; o <<= 1) {
        int u = (t >= o) ? sh[t - o] : 0;
        __syncthreads();
        sh[t] += u;
        __syncthreads();
    }
    if (t < NBUK) { bstart[t] = sh[t] - v; gcur[t] = sh[t] - v; }
    if (t == 0) { bstart[NBUK] = ET; rs[NN] = ET; }
}

__global__ __launch_bounds__(256) void k_bplace(const int4* __restrict__ src4v, const int4* __restrict__ dst4v,
                                                int* __restrict__ gcur, unsigned int* __restrict__ ebuf) {
    __shared__ int bh[NBUK];
    __shared__ int bbase[NBUK];
    for (int i = threadIdx.x; i < NBUK; i += 256) bh[i] = 0;
    __syncthreads();
    int gtid = blockIdx.x * 256 + threadIdx.x;

    int esrc[16];
    int emeta[16];   // (b<<21) | (ldst<<13) | lrank
#pragma unroll
    for (int it = 0; it < 4; it++) {
        int q = gtid + it * (PB * 256);
        bool valid = q < TQ;
        int4 s, d;
        if (valid) {
            if (q < EQ) { s = src4v[q]; d = dst4v[q]; }
            else { int s0 = (q - EQ) * 4; s.x = s0; s.y = s0 + 1; s.z = s0 + 2; s.w = s0 + 3; d = s; }
        } else {
            s.x = s.y = s.z = s.w = 0; d = s;
        }
        int ss[4] = {s.x, s.y, s.z, s.w};
        int dd[4] = {d.x, d.y, d.z, d.w};
#pragma unroll
        for (int k = 0; k < 4; k++) {
            int idx = it * 4 + k;
            if (valid) {
                int b = dd[k] >> 8, l = dd[k] & 255;
                int r = atomicAdd(&bh[b], 1);
                esrc[idx]  = ss[k];
                emeta[idx] = (b << 21) | (l << 13) | r;
            } else {
                emeta[idx] = -1;
            }
        }
    }
    __syncthreads();
    for (int i = threadIdx.x; i < NBUK; i += 256)
        bbase[i] = bh[i] ? atomicAdd(&gcur[i], bh[i]) : 0;
    __syncthreads();
#pragma unroll
    for (int e = 0; e < 16; e++) {
        int me = emeta[e];
        if (me >= 0) {
            int b = me >> 21, l = (me >> 13) & 255, r = me & 8191;
            ebuf[bbase[b] + r] = ((unsigned)l << 24) | (unsigned)esrc[e];
        }
    }
}

__global__ __launch_bounds__(256) void k_csr(const unsigned int* __restrict__ ebuf,
                                             const int* __restrict__ bstart,
                                             int* __restrict__ rs, int* __restrict__ csr) {
    __shared__ int hist[256];
    __shared__ int sh[256];
    __shared__ int cur[256];
    int b = blockIdx.x;
    int t = threadIdx.x;
    int e0 = bstart[b], e1 = bstart[b + 1];
    hist[t] = 0;
    __syncthreads();
    for (int j = e0 + t; j < e1; j += 256)
        atomicAdd(&hist[ebuf[j] >> 24], 1);
    __syncthreads();
    int v = hist[t];
    sh[t] = v;
    __syncthreads();
    for (int o = 1; o < 256; o <<= 1) {
        int u = (t >= o) ? sh[t - o] : 0;
        __syncthreads();
        sh[t] += u;
        __syncthreads();
    }
    int excl = sh[t] - v;
    cur[t] = excl;
    int v0 = b * 256;
    if (v0 + t < NN) rs[v0 + t] = e0 + excl;
    __syncthreads();
    for (int j = e0 + t; j < e1; j += 256) {
        unsigned int e = ebuf[j];
        int l = (int)(e >> 24);
        int r = atomicAdd(&cur[l], 1);
        csr[e0 + r] = (int)(e & 0x00FFFFFFu);
    }
}

// ---------------------------------------------------------------------------
// One-time weight prep: fp16 transposed copies. w1T[n][k] (128x128),
// w2T[n][k] (64x256). Makes GEMM B-fragments single 16B loads.
// ---------------------------------------------------------------------------
__global__ __launch_bounds__(256) void k_wprep(const float* __restrict__ W1, const float* __restrict__ W2,
                                               _Float16* __restrict__ w1T, _Float16* __restrict__ w2T) {
    int idx = blockIdx.x * 256 + threadIdx.x;
    if (idx < 128 * 128) {
        int nn = idx >> 7, k = idx & 127;
        w1T[idx] = (_Float16)W1[k * 128 + nn];
    }
    int i2 = idx - 128 * 128;
    if (i2 >= 0 && i2 < 64 * 256) {
        int nn = i2 >> 8, k = i2 & 255;
        w2T[i2] = (_Float16)W2[k * 64 + nn];
    }
}

// ---------------------------------------------------------------------------
// LDS-free direct MFMA GEMM: xp = x @ W, W given as fp16 transposed [C][K].
// Block = 256 thr = 4 waves, 128 rows. Wave w: rows w*32..+31 as two 16-row
// tiles. A fragments loaded straight from global (fp32 converted in-reg),
// B fragments are 16B f16x8 loads from the L1-resident wT. No LDS, no
// barriers, zero bank conflicts (fix for the 67us latency-bound gemm_mfma:
// MfmaUtil 1.8 / VALUBusy 4.4 / occupancy 23 with 2 barriers per K-chunk).
// AMODE 1: fused conv1 attention epilogue (4 heads; head = t>>1 uniform per
// tile) -> att_s4[row], att_d4[row] via 4-stage shfl_xor reduce over l16.
// AMODE 2: fused conv2 attention (H=1) -> att_s[row], att_d[row].
// ---------------------------------------------------------------------------
template <int K, int C, bool SRCF32, int AMODE>
__global__ __launch_bounds__(256) void gemm_direct(const void* __restrict__ xv,
                                                   const _Float16* __restrict__ wT,
                                                   const float* __restrict__ as_w, const float* __restrict__ ad_w,
                                                   __half* __restrict__ xp,
                                                   float* __restrict__ att_s, float* __restrict__ att_d, int n) {
    constexpr int NT = C / 16;       // 16-col tiles
    const int tid  = threadIdx.x;
    const int w    = tid >> 6;
    const int lane = tid & 63;
    const int quad = lane >> 4;
    const int l16  = lane & 15;
    const long r0  = (long)blockIdx.x * 128;
    const long row0 = r0 + w * 32 + l16;       // a0 fragment row
    const long row1 = row0 + 16;               // a1 fragment row

    f32x4 acc[2][NT];
#pragma unroll
    for (int s = 0; s < 2; s++)
#pragma unroll
        for (int t = 0; t < NT; t++) acc[s][t] = (f32x4){0.f, 0.f, 0.f, 0.f};

#pragma unroll
    for (int ks = 0; ks < K; ks += 32) {
        f16x8 a0 = (f16x8){0, 0, 0, 0, 0, 0, 0, 0};
        f16x8 a1 = (f16x8){0, 0, 0, 0, 0, 0, 0, 0};
        if (SRCF32) {
            if (row0 < n) {
                const float4* p = (const float4*)((const float*)xv + row0 * K + ks) + quad * 2;
                float4 u = p[0], v = p[1];
                a0 = (f16x8){(_Float16)u.x, (_Float16)u.y, (_Float16)u.z, (_Float16)u.w,
                             (_Float16)v.x, (_Float16)v.y, (_Float16)v.z, (_Float16)v.w};
            }
            if (row1 < n) {
                const float4* p = (const float4*)((const float*)xv + row1 * K + ks) + quad * 2;
                float4 u = p[0], v = p[1];
                a1 = (f16x8){(_Float16)u.x, (_Float16)u.y, (_Float16)u.z, (_Float16)u.w,
                             (_Float16)v.x, (_Float16)v.y, (_Float16)v.z, (_Float16)v.w};
            }
        } else {
            if (row0 < n) a0 = *(const f16x8*)((const _Float16*)xv + row0 * K + ks + quad * 8);
            if (row1 < n) a1 = *(const f16x8*)((const _Float16*)xv + row1 * K + ks + quad * 8);
        }
#pragma unroll
        for (int t = 0; t < NT; t++) {
            f16x8 b = *(const f16x8*)(wT + (long)(t * 16 + l16) * K + ks + quad * 8);
            acc[0][t] = __builtin_amdgcn_mfma_f32_16x16x32_f16(a0, b, acc[0][t], 0, 0, 0);
            acc[1][t] = __builtin_amdgcn_mfma_f32_16x16x32_f16(a1, b, acc[1][t], 0, 0, 0);
        }
    }

    // xp write: C/D layout col = l16 (within tile), row = quad*4+rg
#pragma unroll
    for (int sub = 0; sub < 2; sub++) {
        long rb = r0 + w * 32 + sub * 16 + quad * 4;
#pragma unroll
        for (int t = 0; t < NT; t++) {
            int c = t * 16 + l16;
#pragma unroll
            for (int rg = 0; rg < 4; rg++) {
                long row = rb + rg;
                if (row < n) xp[row * (long)C + c] = __float2half(acc[sub][t][rg]);
            }
        }
    }

    if (AMODE == 1) {
        // conv1 attention: 4 heads x 32 ch. col c = t*16+l16 -> head t>>1,
        // within-head idx (t&1)*16+l16.
        float asw[8], adw[8];
#pragma unroll
        for (int t = 0; t < 8; t++) {
            int ci = (t >> 1) * 32 + (t & 1) * 16 + l16;
            asw[t] = as_w[ci];
            adw[t] = ad_w[ci];
        }
#pragma unroll
        for (int sub = 0; sub < 2; sub++) {
#pragma unroll
            for (int rg = 0; rg < 4; rg++) {
                long row = r0 + w * 32 + sub * 16 + quad * 4 + rg;
                float hs[4] = {0.f, 0.f, 0.f, 0.f};
                float hd[4] = {0.f, 0.f, 0.f, 0.f};
#pragma unroll
                for (int t = 0; t < 8; t++) {
                    float av = acc[sub][t][rg];
                    hs[t >> 1] += av * asw[t];
                    hd[t >> 1] += av * adw[t];
                }
#pragma unroll
                for (int h = 0; h < 4; h++) {
                    hs[h] += __shfl_xor(hs[h], 1); hs[h] += __shfl_xor(hs[h], 2);
                    hs[h] += __shfl_xor(hs[h], 4); hs[h] += __shfl_xor(hs[h], 8);
                    hd[h] += __shfl_xor(hd[h], 1); hd[h] += __shfl_xor(hd[h], 2);
                    hd[h] += __shfl_xor(hd[h], 4); hd[h] += __shfl_xor(hd[h], 8);
                }
                if (l16 == 0 && row < n) {
                    ((float4*)att_s)[row] = make_float4(hs[0], hs[1], hs[2], hs[3]);
                    ((float4*)att_d)[row] = make_float4(hd[0], hd[1], hd[2], hd[3]);
                }
            }
        }
    }
    if (AMODE == 2) {
        // conv2 attention: H=1, C=64. col c = t*16+l16.
        float asw[NT], adw[NT];
#pragma unroll
        for (int t = 0; t < NT; t++) {
            asw[t] = as_w[t * 16 + l16];
            adw[t] = ad_w[t * 16 + l16];
        }
#pragma unroll
        for (int sub = 0; sub < 2; sub++) {
#pragma unroll
            for (int rg = 0; rg < 4; rg++) {
                long row = r0 + w * 32 + sub * 16 + quad * 4 + rg;
                float s = 0.f, d = 0.f;
#pragma unroll
                for (int t = 0; t < NT; t++) {
                    float av = acc[sub][t][rg];
                    s += av * asw[t];
                    d += av * adw[t];
                }
                s += __shfl_xor(s, 1); s += __shfl_xor(s, 2); s += __shfl_xor(s, 4); s += __shfl_xor(s, 8);
                d += __shfl_xor(d, 1); d += __shfl_xor(d, 2); d += __shfl_xor(d, 4); d += __shfl_xor(d, 8);
                if (l16 == 0 && row < n) {
                    att_s[row] = s;
                    att_d[row] = d;
                }
            }
        }
    }
}

// ---------------------------------------------------------------------------
// Per-edge exp-weights for conv1, CSR-ordered: one 16-lane group per node.
// ---------------------------------------------------------------------------
__global__ __launch_bounds__(256) void w1prep_node(const int* __restrict__ rs, const int* __restrict__ csr,
                                                   const float4* __restrict__ att_sp4, const float4* __restrict__ att_dp4,
                                                   const float4* __restrict__ att_sg4, const float4* __restrict__ att_dg4,
                                                   float4* __restrict__ wbp4, float4* __restrict__ wbg4) {
    int v = blockIdx.x * 16 + (threadIdx.x >> 4);
    if (v >= NN) return;
    int sl = threadIdx.x & 15;
    int e0 = rs[v], e1 = rs[v + 1];
    float4 dp = att_dp4[v], dg = att_dg4[v];
    auto w = [](float e) { e = (e > 0.f) ? e : NEG * e; return __expf(e); };
    for (int j = e0 + sl; j < e1; j += 16) {
        int s = csr[j];
        float4 sp = att_sp4[s], sg = att_sg4[s];
        float4 wp, wg;
        wp.x = w(sp.x + dp.x); wp.y = w(sp.y + dp.y);
        wp.z = w(sp.z + dp.z); wp.w = w(sp.w + dp.w);
        wg.x = w(sg.x + dg.x); wg.y = w(sg.y + dg.y);
        wg.z = w(sg.z + dg.z); wg.w = w(sg.w + dg.w);
        wbp4[j] = wp;
        wbg4[j] = wg;
    }
}

// ---------------------------------------------------------------------------
// conv1 single-set pass (working-set-split). One wave per dst node;
// quarter-wave qw handles edges j+4k+qw; lane m gathers 16B = ch 8m..8m+7.
// ---------------------------------------------------------------------------
__global__ __launch_bounds__(256) void conv1_pass(const int* __restrict__ rs, const int* __restrict__ csr,
                                                  const uint4* __restrict__ xp,
                                                  const float* __restrict__ wb,
                                                  const float* __restrict__ bias,
                                                  __half* __restrict__ out, int off) {
    int v = blockIdx.x * 4 + (threadIdx.x >> 6);
    if (v >= NN) return;
    int lane = threadIdx.x & 63;
    int qw = lane >> 4;                // quarter-wave: edge offset
    int m = lane & 15;                 // channels 8m..8m+7
    int hd = m >> 2;                   // head index for this lane's channels
    int e0 = rs[v], e1 = rs[v + 1];

    float a[8];
#pragma unroll
    for (int i = 0; i < 8; i++) a[i] = 0.f;
    float d = 0.f;

    int j = e0;
    // full chunks: 16 edges, 4 gathers in flight, no predication
    for (; j + 16 <= e1; j += 16) {
        int s[4]; float w[4]; uint4 r[4];
#pragma unroll
        for (int k = 0; k < 4; k++) s[k] = csr[j + 4 * k + qw];
#pragma unroll
        for (int k = 0; k < 4; k++) w[k] = wb[(j + 4 * k + qw) * 4 + hd];
#pragma unroll
        for (int k = 0; k < 4; k++) r[k] = xp[(long)s[k] * 16 + m];
#pragma unroll
        for (int k = 0; k < 4; k++) {
            d += w[k];
            float2 f0 = __half22float2(*(__half2*)&r[k].x);
            float2 f1 = __half22float2(*(__half2*)&r[k].y);
            float2 f2 = __half22float2(*(__half2*)&r[k].z);
            float2 f3 = __half22float2(*(__half2*)&r[k].w);
            a[0] += w[k] * f0.x; a[1] += w[k] * f0.y;
            a[2] += w[k] * f1.x; a[3] += w[k] * f1.y;
            a[4] += w[k] * f2.x; a[5] += w[k] * f2.y;
            a[6] += w[k] * f3.x; a[7] += w[k] * f3.y;
        }
    }
    // tail: 4 edges per iteration, clamped duplicate gathers with zero weight
    for (; j < e1; j += 4) {
        int jj = j + qw;
        int jc = (jj < e1) ? jj : (e1 - 1);
        int s = csr[jc];
        float w = (jj < e1) ? wb[jc * 4 + hd] : 0.f;
        uint4 r = xp[(long)s * 16 + m];
        d += w;
        float2 f0 = __half22float2(*(__half2*)&r.x);
        float2 f1 = __half22float2(*(__half2*)&r.y);
        float2 f2 = __half22float2(*(__half2*)&r.z);
        float2 f3 = __half22float2(*(__half2*)&r.w);
        a[0] += w * f0.x; a[1] += w * f0.y;
        a[2] += w * f1.x; a[3] += w * f1.y;
        a[4] += w * f2.x; a[5] += w * f2.y;
        a[6] += w * f3.x; a[7] += w * f3.y;
    }

    // combine the four quarters (disjoint edge subsets)
#pragma unroll
    for (int i = 0; i < 8; i++) {
        a[i] += __shfl_xor(a[i], 16);
        a[i] += __shfl_xor(a[i], 32);
    }
    d += __shfl_xor(d, 16);
    d += __shfl_xor(d, 32);

    if (qw == 0) {
        float inv = 1.0f / d;
        const float4* b4 = (const float4*)bias;
        float4 bA = b4[2 * m], bB = b4[2 * m + 1];
        __half2 o01 = __floats2half2_rn(fmaxf(a[0] * inv + bA.x, 0.f), fmaxf(a[1] * inv + bA.y, 0.f));
        __half2 o23 = __floats2half2_rn(fmaxf(a[2] * inv + bA.z, 0.f), fmaxf(a[3] * inv + bA.w, 0.f));
        __half2 o45 = __floats2half2_rn(fmaxf(a[4] * inv + bB.x, 0.f), fmaxf(a[5] * inv + bB.y, 0.f));
        __half2 o67 = __floats2half2_rn(fmaxf(a[6] * inv + bB.z, 0.f), fmaxf(a[7] * inv + bB.w, 0.f));
        uint4 st;
        st.x = *(unsigned int*)&o01;
        st.y = *(unsigned int*)&o23;
        st.z = *(unsigned int*)&o45;
        st.w = *(unsigned int*)&o67;
        *(uint4*)(out + (long)v * 256 + off + 8 * m) = st;
    }
}

// ---------------------------------------------------------------------------
// Single-pass conv2 edge kernel (H=1, C=64, fp16 xp). Weight inline from
// asrc[s] (400KB) + adst[v] register. Quarter-waves; 16-edge full chunks.
// ---------------------------------------------------------------------------
__global__ __launch_bounds__(256) void conv2_edge(const int* __restrict__ rs, const int* __restrict__ csr,
                                                  const __half* __restrict__ xp,
                                                  const float* __restrict__ asrc,
                                                  const float* __restrict__ adst,
                                                  const float* __restrict__ bias,
                                                  float* __restrict__ out) {
    int v = blockIdx.x * 4 + (threadIdx.x >> 6);
    if (v >= NN) return;
    int lane = threadIdx.x & 63;
    int qw = lane >> 4;                // quarter-wave: edge offset
    int m = lane & 15;                 // channels 4m..4m+3
    int e0 = rs[v], e1 = rs[v + 1];
    const uint2* xp2 = (const uint2*)xp;

    float adv = adst[v];
    auto lrexp = [](float e) { e = (e > 0.f) ? e : NEG * e; return __expf(e); };

    float a0 = 0.f, a1 = 0.f, a2 = 0.f, a3 = 0.f, d = 0.f;

    int j = e0;
    // full chunks: 16 edges, 4 gathers in flight, no predication
    for (; j + 16 <= e1; j += 16) {
        int s[4]; float av[4]; uint2 r[4];
#pragma unroll
        for (int k = 0; k < 4; k++) s[k] = csr[j + 4 * k + qw];
#pragma unroll
        for (int k = 0; k < 4; k++) av[k] = asrc[s[k]];
#pragma unroll
        for (int k = 0; k < 4; k++) r[k] = xp2[(long)s[k] * 16 + m];
#pragma unroll
        for (int k = 0; k < 4; k++) {
            float w = lrexp(av[k] + adv);
            d += w;
            float2 x01 = __half22float2(*(__half2*)&r[k].x);
            float2 x23 = __half22float2(*(__half2*)&r[k].y);
            a0 += w * x01.x; a1 += w * x01.y;
            a2 += w * x23.x; a3 += w * x23.y;
        }
    }
    // tail: 4 edges per iteration, clamped
    for (; j < e1; j += 4) {
        int jj = j + qw;
        int jc = (jj < e1) ? jj : (e1 - 1);
        int s = csr[jc];
        float av = asrc[s];
        uint2 r = xp2[(long)s * 16 + m];
        float w = (jj < e1) ? lrexp(av + adv) : 0.f;
        d += w;
        float2 x01 = __half22float2(*(__half2*)&r.x);
        float2 x23 = __half22float2(*(__half2*)&r.y);
        a0 += w * x01.x; a1 += w * x01.y;
        a2 += w * x23.x; a3 += w * x23.y;
    }

    // combine the four quarters
    a0 += __shfl_xor(a0, 16); a1 += __shfl_xor(a1, 16);
    a2 += __shfl_xor(a2, 16); a3 += __shfl_xor(a3, 16);
    d  += __shfl_xor(d, 16);
    a0 += __shfl_xor(a0, 32); a1 += __shfl_xor(a1, 32);
    a2 += __shfl_xor(a2, 32); a3 += __shfl_xor(a3, 32);
    d  += __shfl_xor(d, 32);

    if (qw == 0) {
        float inv = 1.0f / d;
        float4 b4 = *(const float4*)&bias[4 * m];
        float4 o;
        o.x = a0 * inv + b4.x;
        o.y = a1 * inv + b4.y;
        o.z = a2 * inv + b4.z;
        o.w = a3 * inv + b4.w;
        *(float4*)&out[(long)v * 64 + 4 * m] = o;
    }
}

// ---------------------------------------------------------------------------
// Launch
// ---------------------------------------------------------------------------
extern "C" void kernel_launch(void* const* d_in, const int* in_sizes, int n_in,
                              void* d_out, int out_size, void* d_ws, size_t ws_size,
                              hipStream_t stream) {
    const float* x_ppi = (const float*)d_in[0];
    const float* x_go  = (const float*)d_in[1];
    const int*   ei    = (const int*)d_in[2];
    const float* W1    = (const float*)d_in[3];
    const float* as1   = (const float*)d_in[4];
    const float* ad1   = (const float*)d_in[5];
    const float* b1    = (const float*)d_in[6];
    const float* W2    = (const float*)d_in[7];
    const float* as2   = (const float*)d_in[8];
    const float* ad2   = (const float*)d_in[9];
    const float* b2    = (const float*)d_in[10];
    float* out = (float*)d_out;

    char* ws = (char*)d_ws;
    size_t off = 0;
    auto alloc = [&](size_t bytes) -> void* {
        void* p = ws + off;
        off = (off + bytes + 255) & ~(size_t)255;
        return p;
    };
    int* bucketCount = (int*)alloc((size_t)NBUK * 4);
    int* bstart      = (int*)alloc((size_t)(NBUK + 1) * 4);
    int* gcur        = (int*)alloc((size_t)NBUK * 4);
    unsigned int* ebuf = (unsigned int*)alloc((size_t)ET * 4);
    int* rs      = (int*)alloc((size_t)(NN + 1) * 4);
    int* csr     = (int*)alloc((size_t)ET * 4);
    _Float16* w1T = (_Float16*)alloc((size_t)128 * 128 * 2);
    _Float16* w2T = (_Float16*)alloc((size_t)64 * 256 * 2);
    __half* xp_p = (__half*)alloc((size_t)NN * 128 * 2);   // conv1 p-set features
    __half* xp_g = (__half*)alloc((size_t)NN * 128 * 2);   // conv1 g-set features
    __half* xp2  = (__half*)alloc((size_t)NN * 64 * 2);    // conv2 features fp16
    float* attsp = (float*)alloc((size_t)NN * 4 * 4);
    float* attdp = (float*)alloc((size_t)NN * 4 * 4);
    float* attsg = (float*)alloc((size_t)NN * 4 * 4);
    float* attdg = (float*)alloc((size_t)NN * 4 * 4);
    float* asr2  = (float*)alloc((size_t)NN * 4);
    float* ads2  = (float*)alloc((size_t)NN * 4);
    float* wbp   = (float*)alloc((size_t)ET * 16);         // 4 fp32 weights/edge (p)
    float* wbg   = (float*)alloc((size_t)ET * 16);         // 4 fp32 weights/edge (g)
    __half* hbuf = (__half*)alloc((size_t)NN * 256 * 2);   // conv1 output, fp16
    (void)ws_size; (void)in_sizes; (void)n_in; (void)out_size;

    const int GB = (NN + 127) / 128;        // 782 (MFMA gemm blocks)

    // CSR build: two-level counting sort
    hipMemsetAsync(bucketCount, 0, (size_t)NBUK * 4, stream);
    k_bcount<<<PB, 256, 0, stream>>>((const int4*)(ei + EE), bucketCount);
    k_bscan<<<1, 512, 0, stream>>>(bucketCount, bstart, gcur, rs);
    k_bplace<<<PB, 256, 0, stream>>>((const int4*)ei, (const int4*)(ei + EE), gcur, ebuf);
    k_csr<<<NBUK, 256, 0, stream>>>(ebuf, bstart, rs, csr);

    // weight prep (fp16 transposed)
    k_wprep<<<128, 256, 0, stream>>>(W1, W2, w1T, w2T);

    // layer 1: two direct GEMMs with fused attention epilogues
    gemm_direct<128, 128, true, 1><<<GB, 256, 0, stream>>>(x_ppi, w1T, as1, ad1, xp_p, attsp, attdp, NN);
    gemm_direct<128, 128, true, 1><<<GB, 256, 0, stream>>>(x_go, w1T, as1, ad1, xp_g, attsg, attdg, NN);
    w1prep_node<<<(NN + 15) / 16, 256, 0, stream>>>(rs, csr, (const float4*)attsp, (const float4*)attdp,
                                                    (const float4*)attsg, (const float4*)attdg,
                                                    (float4*)wbp, (float4*)wbg);
    // two working-set-split edge passes
    conv1_pass<<<NN / 4, 256, 0, stream>>>(rs, csr, (const uint4*)xp_p, wbp, b1, hbuf, 0);
    conv1_pass<<<NN / 4, 256, 0, stream>>>(rs, csr, (const uint4*)xp_g, wbg, b1, hbuf, 128);

    // layer 2: direct GEMM with fused H=1 attention
    gemm_direct<256, 64, false, 2><<<GB, 256, 0, stream>>>(hbuf, w2T, as2, ad2, xp2, asr2, ads2, NN);
    conv2_edge<<<NN / 4, 256, 0, stream>>>(rs, csr, xp2, asr2, ads2, b2, out);
}

// Round 9
// 494.465 us; speedup vs baseline: 1.4028x; 1.0227x over previous
//
#include <hip/hip_runtime.h>
#include <hip/hip_fp16.h>

// Problem constants (fixed by the reference)
constexpr int NN = 100000;          // nodes
constexpr int EE = 1600000;         // edges (without self loops)
constexpr int ET = EE + NN;         // edges + self loops
constexpr int EQ = EE / 4;          // 400000 int4 groups of real edges
constexpr int TQ = ET / 4;          // 425000 int4 groups total (ET % 4 == 0)
constexpr int NBUK = (NN + 255) / 256;  // 391 dst-buckets of 256 nodes
constexpr int PB = 416;             // blocks for bucket count/place (416*256*4 >= TQ)
constexpr float NEG = 0.2f;

typedef _Float16 f16x8 __attribute__((ext_vector_type(8)));
typedef _Float16 f16x4 __attribute__((ext_vector_type(4)));
typedef float    f32x4 __attribute__((ext_vector_type(4)));

// ---------------------------------------------------------------------------
// CSR build, two-level counting sort (bucket = dst>>8, 391 buckets).
// ---------------------------------------------------------------------------
__global__ __launch_bounds__(256) void k_bcount(const int4* __restrict__ dst4v,
                                                int* __restrict__ bucketCount) {
    __shared__ int bh[NBUK];
    for (int i = threadIdx.x; i < NBUK; i += 256) bh[i] = 0;
    __syncthreads();
    int gtid = blockIdx.x * 256 + threadIdx.x;
    for (int q = gtid; q < TQ; q += PB * 256) {
        int4 d;
        if (q < EQ) {
            d = dst4v[q];
        } else {
            int s0 = (q - EQ) * 4;       // self loops: dst = node id
            d.x = s0; d.y = s0 + 1; d.z = s0 + 2; d.w = s0 + 3;
        }
        atomicAdd(&bh[d.x >> 8], 1);
        atomicAdd(&bh[d.y >> 8], 1);
        atomicAdd(&bh[d.z >> 8], 1);
        atomicAdd(&bh[d.w >> 8], 1);
    }
    __syncthreads();
    for (int i = threadIdx.x; i < NBUK; i += 256)
        if (bh[i]) atomicAdd(&bucketCount[i], bh[i]);
}

__global__ __launch_bounds__(512) void k_bscan(const int* __restrict__ bucketCount,
                                               int* __restrict__ bstart, int* __restrict__ gcur,
                                               int* __restrict__ rs) {
    __shared__ int sh[512];
    int t = threadIdx.x;
    int v = (t < NBUK) ? bucketCount[t] : 0;
    sh[t] = v;
    __syncthreads();
    for (int o = 1; o < 512; o <<= 1) {
        int u = (t >= o) ? sh[t - o] : 0;
        __syncthreads();
        sh[t] += u;
        __syncthreads();
    }
    if (t < NBUK) { bstart[t] = sh[t] - v; gcur[t] = sh[t] - v; }
    if (t == 0) { bstart[NBUK] = ET; rs[NN] = ET; }
}

__global__ __launch_bounds__(256) void k_bplace(const int4* __restrict__ src4v, const int4* __restrict__ dst4v,
                                                int* __restrict__ gcur, unsigned int* __restrict__ ebuf) {
    __shared__ int bh[NBUK];
    __shared__ int bbase[NBUK];
    for (int i = threadIdx.x; i < NBUK; i += 256) bh[i] = 0;
    __syncthreads();
    int gtid = blockIdx.x * 256 + threadIdx.x;

    int esrc[16];
    int emeta[16];   // (b<<21) | (ldst<<13) | lrank
#pragma unroll
    for (int it = 0; it < 4; it++) {
        int q = gtid + it * (PB * 256);
        bool valid = q < TQ;
        int4 s, d;
        if (valid) {
            if (q < EQ) { s = src4v[q]; d = dst4v[q]; }
            else { int s0 = (q - EQ) * 4; s.x = s0; s.y = s0 + 1; s.z = s0 + 2; s.w = s0 + 3; d = s; }
        } else {
            s.x = s.y = s.z = s.w = 0; d = s;
        }
        int ss[4] = {s.x, s.y, s.z, s.w};
        int dd[4] = {d.x, d.y, d.z, d.w};
#pragma unroll
        for (int k = 0; k < 4; k++) {
            int idx = it * 4 + k;
            if (valid) {
                int b = dd[k] >> 8, l = dd[k] & 255;
                int r = atomicAdd(&bh[b], 1);
                esrc[idx]  = ss[k];
                emeta[idx] = (b << 21) | (l << 13) | r;
            } else {
                emeta[idx] = -1;
            }
        }
    }
    __syncthreads();
    for (int i = threadIdx.x; i < NBUK; i += 256)
        bbase[i] = bh[i] ? atomicAdd(&gcur[i], bh[i]) : 0;
    __syncthreads();
#pragma unroll
    for (int e = 0; e < 16; e++) {
        int me = emeta[e];
        if (me >= 0) {
            int b = me >> 21, l = (me >> 13) & 255, r = me & 8191;
            ebuf[bbase[b] + r] = ((unsigned)l << 24) | (unsigned)esrc[e];
        }
    }
}

__global__ __launch_bounds__(256) void k_csr(const unsigned int* __restrict__ ebuf,
                                             const int* __restrict__ bstart,
                                             int* __restrict__ rs, int* __restrict__ csr) {
    __shared__ int hist[256];
    __shared__ int sh[256];
    __shared__ int cur[256];
    int b = blockIdx.x;
    int t = threadIdx.x;
    int e0 = bstart[b], e1 = bstart[b + 1];
    hist[t] = 0;
    __syncthreads();
    for (int j = e0 + t; j < e1; j += 256)
        atomicAdd(&hist[ebuf[j] >> 24], 1);
    __syncthreads();
    int v = hist[t];
    sh[t] = v;
    __syncthreads();
    for (int o = 1; o < 256; o <<= 1) {
        int u = (t >= o) ? sh[t - o] : 0;
        __syncthreads();
        sh[t] += u;
        __syncthreads();
    }
    int excl = sh[t] - v;
    cur[t] = excl;
    int v0 = b * 256;
    if (v0 + t < NN) rs[v0 + t] = e0 + excl;
    __syncthreads();
    for (int j = e0 + t; j < e1; j += 256) {
        unsigned int e = ebuf[j];
        int l = (int)(e >> 24);
        int r = atomicAdd(&cur[l], 1);
        csr[e0 + r] = (int)(e & 0x00FFFFFFu);
    }
}

// ---------------------------------------------------------------------------
// One-time weight prep: fp16 transposed copies. w1T[n][k] (128x128),
// w2T[n][k] (64x256). Makes GEMM B-fragments single 16B loads.
// ---------------------------------------------------------------------------
__global__ __launch_bounds__(256) void k_wprep(const float* __restrict__ W1, const float* __restrict__ W2,
                                               _Float16* __restrict__ w1T, _Float16* __restrict__ w2T) {
    int idx = blockIdx.x * 256 + threadIdx.x;
    if (idx < 128 * 128) {
        int nn = idx >> 7, k = idx & 127;
        w1T[idx] = (_Float16)W1[k * 128 + nn];
    }
    int i2 = idx - 128 * 128;
    if (i2 >= 0 && i2 < 64 * 256) {
        int nn = i2 >> 8, k = i2 & 255;
        w2T[i2] = (_Float16)W2[k * 64 + nn];
    }
}

// ---------------------------------------------------------------------------
// LDS-free direct MFMA GEMM: xp = x @ W, W given as fp16 transposed [C][K].
// AMODE 1: fused conv1 attention epilogue -> att_s4[row], att_d4[row].
// AMODE 2: fused conv2 attention (H=1) -> att_s[row], att_d[row].
// ---------------------------------------------------------------------------
template <int K, int C, bool SRCF32, int AMODE>
__global__ __launch_bounds__(256) void gemm_direct(const void* __restrict__ xv,
                                                   const _Float16* __restrict__ wT,
                                                   const float* __restrict__ as_w, const float* __restrict__ ad_w,
                                                   __half* __restrict__ xp,
                                                   float* __restrict__ att_s, float* __restrict__ att_d, int n) {
    constexpr int NT = C / 16;       // 16-col tiles
    const int tid  = threadIdx.x;
    const int w    = tid >> 6;
    const int lane = tid & 63;
    const int quad = lane >> 4;
    const int l16  = lane & 15;
    const long r0  = (long)blockIdx.x * 128;
    const long row0 = r0 + w * 32 + l16;       // a0 fragment row
    const long row1 = row0 + 16;               // a1 fragment row

    f32x4 acc[2][NT];
#pragma unroll
    for (int s = 0; s < 2; s++)
#pragma unroll
        for (int t = 0; t < NT; t++) acc[s][t] = (f32x4){0.f, 0.f, 0.f, 0.f};

#pragma unroll
    for (int ks = 0; ks < K; ks += 32) {
        f16x8 a0 = (f16x8){0, 0, 0, 0, 0, 0, 0, 0};
        f16x8 a1 = (f16x8){0, 0, 0, 0, 0, 0, 0, 0};
        if (SRCF32) {
            if (row0 < n) {
                const float4* p = (const float4*)((const float*)xv + row0 * K + ks) + quad * 2;
                float4 u = p[0], v = p[1];
                a0 = (f16x8){(_Float16)u.x, (_Float16)u.y, (_Float16)u.z, (_Float16)u.w,
                             (_Float16)v.x, (_Float16)v.y, (_Float16)v.z, (_Float16)v.w};
            }
            if (row1 < n) {
                const float4* p = (const float4*)((const float*)xv + row1 * K + ks) + quad * 2;
                float4 u = p[0], v = p[1];
                a1 = (f16x8){(_Float16)u.x, (_Float16)u.y, (_Float16)u.z, (_Float16)u.w,
                             (_Float16)v.x, (_Float16)v.y, (_Float16)v.z, (_Float16)v.w};
            }
        } else {
            if (row0 < n) a0 = *(const f16x8*)((const _Float16*)xv + row0 * K + ks + quad * 8);
            if (row1 < n) a1 = *(const f16x8*)((const _Float16*)xv + row1 * K + ks + quad * 8);
        }
#pragma unroll
        for (int t = 0; t < NT; t++) {
            f16x8 b = *(const f16x8*)(wT + (long)(t * 16 + l16) * K + ks + quad * 8);
            acc[0][t] = __builtin_amdgcn_mfma_f32_16x16x32_f16(a0, b, acc[0][t], 0, 0, 0);
            acc[1][t] = __builtin_amdgcn_mfma_f32_16x16x32_f16(a1, b, acc[1][t], 0, 0, 0);
        }
    }

    // xp write: C/D layout col = l16 (within tile), row = quad*4+rg
#pragma unroll
    for (int sub = 0; sub < 2; sub++) {
        long rb = r0 + w * 32 + sub * 16 + quad * 4;
#pragma unroll
        for (int t = 0; t < NT; t++) {
            int c = t * 16 + l16;
#pragma unroll
            for (int rg = 0; rg < 4; rg++) {
                long row = rb + rg;
                if (row < n) xp[row * (long)C + c] = __float2half(acc[sub][t][rg]);
            }
        }
    }

    if (AMODE == 1) {
        float asw[8], adw[8];
#pragma unroll
        for (int t = 0; t < 8; t++) {
            int ci = (t >> 1) * 32 + (t & 1) * 16 + l16;
            asw[t] = as_w[ci];
            adw[t] = ad_w[ci];
        }
#pragma unroll
        for (int sub = 0; sub < 2; sub++) {
#pragma unroll
            for (int rg = 0; rg < 4; rg++) {
                long row = r0 + w * 32 + sub * 16 + quad * 4 + rg;
                float hs[4] = {0.f, 0.f, 0.f, 0.f};
                float hd[4] = {0.f, 0.f, 0.f, 0.f};
#pragma unroll
                for (int t = 0; t < 8; t++) {
                    float av = acc[sub][t][rg];
                    hs[t >> 1] += av * asw[t];
                    hd[t >> 1] += av * adw[t];
                }
#pragma unroll
                for (int h = 0; h < 4; h++) {
                    hs[h] += __shfl_xor(hs[h], 1); hs[h] += __shfl_xor(hs[h], 2);
                    hs[h] += __shfl_xor(hs[h], 4); hs[h] += __shfl_xor(hs[h], 8);
                    hd[h] += __shfl_xor(hd[h], 1); hd[h] += __shfl_xor(hd[h], 2);
                    hd[h] += __shfl_xor(hd[h], 4); hd[h] += __shfl_xor(hd[h], 8);
                }
                if (l16 == 0 && row < n) {
                    ((float4*)att_s)[row] = make_float4(hs[0], hs[1], hs[2], hs[3]);
                    ((float4*)att_d)[row] = make_float4(hd[0], hd[1], hd[2], hd[3]);
                }
            }
        }
    }
    if (AMODE == 2) {
        float asw[NT], adw[NT];
#pragma unroll
        for (int t = 0; t < NT; t++) {
            asw[t] = as_w[t * 16 + l16];
            adw[t] = ad_w[t * 16 + l16];
        }
#pragma unroll
        for (int sub = 0; sub < 2; sub++) {
#pragma unroll
            for (int rg = 0; rg < 4; rg++) {
                long row = r0 + w * 32 + sub * 16 + quad * 4 + rg;
                float s = 0.f, d = 0.f;
#pragma unroll
                for (int t = 0; t < NT; t++) {
                    float av = acc[sub][t][rg];
                    s += av * asw[t];
                    d += av * adw[t];
                }
                s += __shfl_xor(s, 1); s += __shfl_xor(s, 2); s += __shfl_xor(s, 4); s += __shfl_xor(s, 8);
                d += __shfl_xor(d, 1); d += __shfl_xor(d, 2); d += __shfl_xor(d, 4); d += __shfl_xor(d, 8);
                if (l16 == 0 && row < n) {
                    att_s[row] = s;
                    att_d[row] = d;
                }
            }
        }
    }
}

// ---------------------------------------------------------------------------
// conv1 single-set pass with INLINE attention weights (w1prep deleted).
// Per edge, lane gathers 4B att_s[s][hd] from the 1.6MB per-pass table and
// computes exp(lrelu(.)) in-VALU (52% busy -> headroom). Same load count per
// edge as the streamed-wb version (csr, att|wb, xp). One wave per dst node;
// quarter-wave qw handles edges j+4k+qw; lane m gathers 16B = ch 8m..8m+7.
// ---------------------------------------------------------------------------
__global__ __launch_bounds__(256) void conv1_pass(const int* __restrict__ rs, const int* __restrict__ csr,
                                                  const uint4* __restrict__ xp,
                                                  const float* __restrict__ att_s,   // [NN][4]
                                                  const float* __restrict__ att_d,   // [NN][4]
                                                  const float* __restrict__ bias,
                                                  __half* __restrict__ out, int off) {
    int v = blockIdx.x * 4 + (threadIdx.x >> 6);
    if (v >= NN) return;
    int lane = threadIdx.x & 63;
    int qw = lane >> 4;                // quarter-wave: edge offset
    int m = lane & 15;                 // channels 8m..8m+7
    int hd = m >> 2;                   // head index for this lane's channels
    int e0 = rs[v], e1 = rs[v + 1];

    float adv = att_d[v * 4 + hd];
    auto lrexp = [](float e) { e = (e > 0.f) ? e : NEG * e; return __expf(e); };

    float a[8];
#pragma unroll
    for (int i = 0; i < 8; i++) a[i] = 0.f;
    float d = 0.f;

    int j = e0;
    // full chunks: 16 edges, 4 gathers in flight, no predication
    for (; j + 16 <= e1; j += 16) {
        int s[4]; float av[4]; uint4 r[4];
#pragma unroll
        for (int k = 0; k < 4; k++) s[k] = csr[j + 4 * k + qw];
#pragma unroll
        for (int k = 0; k < 4; k++) av[k] = att_s[s[k] * 4 + hd];
#pragma unroll
        for (int k = 0; k < 4; k++) r[k] = xp[(long)s[k] * 16 + m];
#pragma unroll
        for (int k = 0; k < 4; k++) {
            float w = lrexp(av[k] + adv);
            d += w;
            float2 f0 = __half22float2(*(__half2*)&r[k].x);
            float2 f1 = __half22float2(*(__half2*)&r[k].y);
            float2 f2 = __half22float2(*(__half2*)&r[k].z);
            float2 f3 = __half22float2(*(__half2*)&r[k].w);
            a[0] += w * f0.x; a[1] += w * f0.y;
            a[2] += w * f1.x; a[3] += w * f1.y;
            a[4] += w * f2.x; a[5] += w * f2.y;
            a[6] += w * f3.x; a[7] += w * f3.y;
        }
    }
    // tail: 4 edges per iteration, clamped duplicate gathers with zero weight
    for (; j < e1; j += 4) {
        int jj = j + qw;
        int jc = (jj < e1) ? jj : (e1 - 1);
        int s = csr[jc];
        float av = att_s[s * 4 + hd];
        uint4 r = xp[(long)s * 16 + m];
        float w = (jj < e1) ? lrexp(av + adv) : 0.f;
        d += w;
        float2 f0 = __half22float2(*(__half2*)&r.x);
        float2 f1 = __half22float2(*(__half2*)&r.y);
        float2 f2 = __half22float2(*(__half2*)&r.z);
        float2 f3 = __half22float2(*(__half2*)&r.w);
        a[0] += w * f0.x; a[1] += w * f0.y;
        a[2] += w * f1.x; a[3] += w * f1.y;
        a[4] += w * f2.x; a[5] += w * f2.y;
        a[6] += w * f3.x; a[7] += w * f3.y;
    }

    // combine the four quarters (disjoint edge subsets)
#pragma unroll
    for (int i = 0; i < 8; i++) {
        a[i] += __shfl_xor(a[i], 16);
        a[i] += __shfl_xor(a[i], 32);
    }
    d += __shfl_xor(d, 16);
    d += __shfl_xor(d, 32);

    if (qw == 0) {
        float inv = 1.0f / d;
        const float4* b4 = (const float4*)bias;
        float4 bA = b4[2 * m], bB = b4[2 * m + 1];
        __half2 o01 = __floats2half2_rn(fmaxf(a[0] * inv + bA.x, 0.f), fmaxf(a[1] * inv + bA.y, 0.f));
        __half2 o23 = __floats2half2_rn(fmaxf(a[2] * inv + bA.z, 0.f), fmaxf(a[3] * inv + bA.w, 0.f));
        __half2 o45 = __floats2half2_rn(fmaxf(a[4] * inv + bB.x, 0.f), fmaxf(a[5] * inv + bB.y, 0.f));
        __half2 o67 = __floats2half2_rn(fmaxf(a[6] * inv + bB.z, 0.f), fmaxf(a[7] * inv + bB.w, 0.f));
        uint4 st;
        st.x = *(unsigned int*)&o01;
        st.y = *(unsigned int*)&o23;
        st.z = *(unsigned int*)&o45;
        st.w = *(unsigned int*)&o67;
        *(uint4*)(out + (long)v * 256 + off + 8 * m) = st;
    }
}

// ---------------------------------------------------------------------------
// Single-pass conv2 edge kernel (H=1, C=64, fp16 xp). Weight inline from
// asrc[s] (400KB) + adst[v] register. Quarter-waves; 16-edge full chunks.
// ---------------------------------------------------------------------------
__global__ __launch_bounds__(256) void conv2_edge(const int* __restrict__ rs, const int* __restrict__ csr,
                                                  const __half* __restrict__ xp,
                                                  const float* __restrict__ asrc,
                                                  const float* __restrict__ adst,
                                                  const float* __restrict__ bias,
                                                  float* __restrict__ out) {
    int v = blockIdx.x * 4 + (threadIdx.x >> 6);
    if (v >= NN) return;
    int lane = threadIdx.x & 63;
    int qw = lane >> 4;                // quarter-wave: edge offset
    int m = lane & 15;                 // channels 4m..4m+3
    int e0 = rs[v], e1 = rs[v + 1];
    const uint2* xp2 = (const uint2*)xp;

    float adv = adst[v];
    auto lrexp = [](float e) { e = (e > 0.f) ? e : NEG * e; return __expf(e); };

    float a0 = 0.f, a1 = 0.f, a2 = 0.f, a3 = 0.f, d = 0.f;

    int j = e0;
    // full chunks: 16 edges, 4 gathers in flight, no predication
    for (; j + 16 <= e1; j += 16) {
        int s[4]; float av[4]; uint2 r[4];
#pragma unroll
        for (int k = 0; k < 4; k++) s[k] = csr[j + 4 * k + qw];
#pragma unroll
        for (int k = 0; k < 4; k++) av[k] = asrc[s[k]];
#pragma unroll
        for (int k = 0; k < 4; k++) r[k] = xp2[(long)s[k] * 16 + m];
#pragma unroll
        for (int k = 0; k < 4; k++) {
            float w = lrexp(av[k] + adv);
            d += w;
            float2 x01 = __half22float2(*(__half2*)&r[k].x);
            float2 x23 = __half22float2(*(__half2*)&r[k].y);
            a0 += w * x01.x; a1 += w * x01.y;
            a2 += w * x23.x; a3 += w * x23.y;
        }
    }
    // tail: 4 edges per iteration, clamped
    for (; j < e1; j += 4) {
        int jj = j + qw;
        int jc = (jj < e1) ? jj : (e1 - 1);
        int s = csr[jc];
        float av = asrc[s];
        uint2 r = xp2[(long)s * 16 + m];
        float w = (jj < e1) ? lrexp(av + adv) : 0.f;
        d += w;
        float2 x01 = __half22float2(*(__half2*)&r.x);
        float2 x23 = __half22float2(*(__half2*)&r.y);
        a0 += w * x01.x; a1 += w * x01.y;
        a2 += w * x23.x; a3 += w * x23.y;
    }

    // combine the four quarters
    a0 += __shfl_xor(a0, 16); a1 += __shfl_xor(a1, 16);
    a2 += __shfl_xor(a2, 16); a3 += __shfl_xor(a3, 16);
    d  += __shfl_xor(d, 16);
    a0 += __shfl_xor(a0, 32); a1 += __shfl_xor(a1, 32);
    a2 += __shfl_xor(a2, 32); a3 += __shfl_xor(a3, 32);
    d  += __shfl_xor(d, 32);

    if (qw == 0) {
        float inv = 1.0f / d;
        float4 b4 = *(const float4*)&bias[4 * m];
        float4 o;
        o.x = a0 * inv + b4.x;
        o.y = a1 * inv + b4.y;
        o.z = a2 * inv + b4.z;
        o.w = a3 * inv + b4.w;
        *(float4*)&out[(long)v * 64 + 4 * m] = o;
    }
}

// ---------------------------------------------------------------------------
// Launch
// ---------------------------------------------------------------------------
extern "C" void kernel_launch(void* const* d_in, const int* in_sizes, int n_in,
                              void* d_out, int out_size, void* d_ws, size_t ws_size,
                              hipStream_t stream) {
    const float* x_ppi = (const float*)d_in[0];
    const float* x_go  = (const float*)d_in[1];
    const int*   ei    = (const int*)d_in[2];
    const float* W1    = (const float*)d_in[3];
    const float* as1   = (const float*)d_in[4];
    const float* ad1   = (const float*)d_in[5];
    const float* b1    = (const float*)d_in[6];
    const float* W2    = (const float*)d_in[7];
    const float* as2   = (const float*)d_in[8];
    const float* ad2   = (const float*)d_in[9];
    const float* b2    = (const float*)d_in[10];
    float* out = (float*)d_out;

    char* ws = (char*)d_ws;
    size_t off = 0;
    auto alloc = [&](size_t bytes) -> void* {
        void* p = ws + off;
        off = (off + bytes + 255) & ~(size_t)255;
        return p;
    };
    int* bucketCount = (int*)alloc((size_t)NBUK * 4);
    int* bstart      = (int*)alloc((size_t)(NBUK + 1) * 4);
    int* gcur        = (int*)alloc((size_t)NBUK * 4);
    unsigned int* ebuf = (unsigned int*)alloc((size_t)ET * 4);
    int* rs      = (int*)alloc((size_t)(NN + 1) * 4);
    int* csr     = (int*)alloc((size_t)ET * 4);
    _Float16* w1T = (_Float16*)alloc((size_t)128 * 128 * 2);
    _Float16* w2T = (_Float16*)alloc((size_t)64 * 256 * 2);
    __half* xp_p = (__half*)alloc((size_t)NN * 128 * 2);   // conv1 p-set features
    __half* xp_g = (__half*)alloc((size_t)NN * 128 * 2);   // conv1 g-set features
    __half* xp2  = (__half*)alloc((size_t)NN * 64 * 2);    // conv2 features fp16
    float* attsp = (float*)alloc((size_t)NN * 4 * 4);
    float* attdp = (float*)alloc((size_t)NN * 4 * 4);
    float* attsg = (float*)alloc((size_t)NN * 4 * 4);
    float* attdg = (float*)alloc((size_t)NN * 4 * 4);
    float* asr2  = (float*)alloc((size_t)NN * 4);
    float* ads2  = (float*)alloc((size_t)NN * 4);
    __half* hbuf = (__half*)alloc((size_t)NN * 256 * 2);   // conv1 output, fp16
    (void)ws_size; (void)in_sizes; (void)n_in; (void)out_size;

    const int GB = (NN + 127) / 128;        // 782 (MFMA gemm blocks)

    // CSR build: two-level counting sort
    hipMemsetAsync(bucketCount, 0, (size_t)NBUK * 4, stream);
    k_bcount<<<PB, 256, 0, stream>>>((const int4*)(ei + EE), bucketCount);
    k_bscan<<<1, 512, 0, stream>>>(bucketCount, bstart, gcur, rs);
    k_bplace<<<PB, 256, 0, stream>>>((const int4*)ei, (const int4*)(ei + EE), gcur, ebuf);
    k_csr<<<NBUK, 256, 0, stream>>>(ebuf, bstart, rs, csr);

    // weight prep (fp16 transposed)
    k_wprep<<<128, 256, 0, stream>>>(W1, W2, w1T, w2T);

    // layer 1: two direct GEMMs with fused attention epilogues
    gemm_direct<128, 128, true, 1><<<GB, 256, 0, stream>>>(x_ppi, w1T, as1, ad1, xp_p, attsp, attdp, NN);
    gemm_direct<128, 128, true, 1><<<GB, 256, 0, stream>>>(x_go, w1T, as1, ad1, xp_g, attsg, attdg, NN);
    // two working-set-split edge passes, attention weights computed inline
    conv1_pass<<<NN / 4, 256, 0, stream>>>(rs, csr, (const uint4*)xp_p, attsp, attdp, b1, hbuf, 0);
    conv1_pass<<<NN / 4, 256, 0, stream>>>(rs, csr, (const uint4*)xp_g, attsg, attdg, b1, hbuf, 128);

    // layer 2: direct GEMM with fused H=1 attention
    gemm_direct<256, 64, false, 2><<<GB, 256, 0, stream>>>(hbuf, w2T, as2, ad2, xp2, asr2, ads2, NN);
    conv2_edge<<<NN / 4, 256, 0, stream>>>(rs, csr, xp2, asr2, ads2, b2, out);
}

// Round 10
// 473.768 us; speedup vs baseline: 1.4640x; 1.0437x over previous
//
#include <hip/hip_runtime.h>
#include <hip/hip_fp16.h>

// Problem constants (fixed by the reference)
constexpr int NN = 100000;          // nodes
constexpr int EE = 1600000;         // edges (without self loops)
constexpr int ET = EE + NN;         // edges + self loops
constexpr int EQ = EE / 4;          // 400000 int4 groups of real edges
constexpr int TQ = ET / 4;          // 425000 int4 groups total (ET % 4 == 0)
constexpr int NBUK = (NN + 255) / 256;  // 391 dst-buckets of 256 nodes
constexpr int PB = 416;             // blocks for bucket count/place
constexpr int GB = (NN + 127) / 128;    // 782 MFMA gemm blocks
constexpr float NEG = 0.2f;

typedef _Float16 f16x8 __attribute__((ext_vector_type(8)));
typedef float    f32x4 __attribute__((ext_vector_type(4)));

// ---------------------------------------------------------------------------
// One-time prep: fp16 transposed weights + zero bucketCount (folds memset).
// ---------------------------------------------------------------------------
__global__ __launch_bounds__(256) void k_wprep0(const float* __restrict__ W1, const float* __restrict__ W2,
                                                _Float16* __restrict__ w1T, _Float16* __restrict__ w2T,
                                                int* __restrict__ bucketCount) {
    if (blockIdx.x == 0) {
        for (int i = threadIdx.x; i < NBUK; i += 256) bucketCount[i] = 0;
    }
    int idx = blockIdx.x * 256 + threadIdx.x;
    if (idx < 128 * 128) {
        int nn = idx >> 7, k = idx & 127;
        w1T[idx] = (_Float16)W1[k * 128 + nn];
    }
    int i2 = idx - 128 * 128;
    if (i2 >= 0 && i2 < 64 * 256) {
        int nn = i2 >> 8, k = i2 & 255;
        w2T[i2] = (_Float16)W2[k * 64 + nn];
    }
}

// ---------------------------------------------------------------------------
// LDS-free direct MFMA GEMM body (device fn).
// OUTM 0: packed xpc {p0,p1,g0,g1} per channel pair, row stride 256 halves,
//         set index SET (0=p -> +0, 1=g -> +2).
// OUTM 1: plain fp16 row of C halves.
// AMODE 1: conv1 attention epilogue -> att_s/att_d float2[NN*4] tables,
//          writes component SET of each float2 (p=.x, g=.y).
// AMODE 2: conv2 attention (H=1) -> att_s[row], att_d[row] plain floats.
// ---------------------------------------------------------------------------
template <int K, int C, bool SRCF32, int AMODE, int OUTM, int SET>
__device__ __forceinline__ void gemm_dev(int bx, const void* __restrict__ xv,
                                         const _Float16* __restrict__ wT,
                                         const float* __restrict__ as_w, const float* __restrict__ ad_w,
                                         __half* __restrict__ xp,
                                         float* __restrict__ att_s, float* __restrict__ att_d, int n) {
    constexpr int NT = C / 16;       // 16-col tiles
    const int tid  = threadIdx.x;
    const int w    = tid >> 6;
    const int lane = tid & 63;
    const int quad = lane >> 4;
    const int l16  = lane & 15;
    const long r0  = (long)bx * 128;
    const long row0 = r0 + w * 32 + l16;       // a0 fragment row
    const long row1 = row0 + 16;               // a1 fragment row

    f32x4 acc[2][NT];
#pragma unroll
    for (int s = 0; s < 2; s++)
#pragma unroll
        for (int t = 0; t < NT; t++) acc[s][t] = (f32x4){0.f, 0.f, 0.f, 0.f};

#pragma unroll
    for (int ks = 0; ks < K; ks += 32) {
        f16x8 a0 = (f16x8){0, 0, 0, 0, 0, 0, 0, 0};
        f16x8 a1 = (f16x8){0, 0, 0, 0, 0, 0, 0, 0};
        if (SRCF32) {
            if (row0 < n) {
                const float4* p = (const float4*)((const float*)xv + row0 * K + ks) + quad * 2;
                float4 u = p[0], v = p[1];
                a0 = (f16x8){(_Float16)u.x, (_Float16)u.y, (_Float16)u.z, (_Float16)u.w,
                             (_Float16)v.x, (_Float16)v.y, (_Float16)v.z, (_Float16)v.w};
            }
            if (row1 < n) {
                const float4* p = (const float4*)((const float*)xv + row1 * K + ks) + quad * 2;
                float4 u = p[0], v = p[1];
                a1 = (f16x8){(_Float16)u.x, (_Float16)u.y, (_Float16)u.z, (_Float16)u.w,
                             (_Float16)v.x, (_Float16)v.y, (_Float16)v.z, (_Float16)v.w};
            }
        } else {
            if (row0 < n) a0 = *(const f16x8*)((const _Float16*)xv + row0 * K + ks + quad * 8);
            if (row1 < n) a1 = *(const f16x8*)((const _Float16*)xv + row1 * K + ks + quad * 8);
        }
#pragma unroll
        for (int t = 0; t < NT; t++) {
            f16x8 b = *(const f16x8*)(wT + (long)(t * 16 + l16) * K + ks + quad * 8);
            acc[0][t] = __builtin_amdgcn_mfma_f32_16x16x32_f16(a0, b, acc[0][t], 0, 0, 0);
            acc[1][t] = __builtin_amdgcn_mfma_f32_16x16x32_f16(a1, b, acc[1][t], 0, 0, 0);
        }
    }

    // xp write: C/D layout col = l16 (within tile), row = quad*4+rg
#pragma unroll
    for (int sub = 0; sub < 2; sub++) {
        long rb = r0 + w * 32 + sub * 16 + quad * 4;
#pragma unroll
        for (int t = 0; t < NT; t++) {
            int c = t * 16 + l16;
#pragma unroll
            for (int rg = 0; rg < 4; rg++) {
                long row = rb + rg;
                if (row < n) {
                    __half hv = __float2half(acc[sub][t][rg]);
                    if (OUTM == 0)
                        xp[row * 256 + ((c >> 1) << 2) + (c & 1) + SET * 2] = hv;
                    else
                        xp[row * (long)C + c] = hv;
                }
            }
        }
    }

    if (AMODE == 1) {
        // 4 heads x 32 ch; col c = t*16+l16 -> head t>>1.
        float asw[8], adw[8];
#pragma unroll
        for (int t = 0; t < 8; t++) {
            int ci = (t >> 1) * 32 + (t & 1) * 16 + l16;
            asw[t] = as_w[ci];
            adw[t] = ad_w[ci];
        }
#pragma unroll
        for (int sub = 0; sub < 2; sub++) {
#pragma unroll
            for (int rg = 0; rg < 4; rg++) {
                long row = r0 + w * 32 + sub * 16 + quad * 4 + rg;
                float hs[4] = {0.f, 0.f, 0.f, 0.f};
                float hd[4] = {0.f, 0.f, 0.f, 0.f};
#pragma unroll
                for (int t = 0; t < 8; t++) {
                    float av = acc[sub][t][rg];
                    hs[t >> 1] += av * asw[t];
                    hd[t >> 1] += av * adw[t];
                }
#pragma unroll
                for (int h = 0; h < 4; h++) {
                    hs[h] += __shfl_xor(hs[h], 1); hs[h] += __shfl_xor(hs[h], 2);
                    hs[h] += __shfl_xor(hs[h], 4); hs[h] += __shfl_xor(hs[h], 8);
                    hd[h] += __shfl_xor(hd[h], 1); hd[h] += __shfl_xor(hd[h], 2);
                    hd[h] += __shfl_xor(hd[h], 4); hd[h] += __shfl_xor(hd[h], 8);
                }
                if (l16 == 0 && row < n) {
                    // float2 tables [NN*4]: component SET (p=.x, g=.y)
#pragma unroll
                    for (int h = 0; h < 4; h++) {
                        att_s[row * 8 + h * 2 + SET] = hs[h];
                        att_d[row * 8 + h * 2 + SET] = hd[h];
                    }
                }
            }
        }
    }
    if (AMODE == 2) {
        float asw[NT], adw[NT];
#pragma unroll
        for (int t = 0; t < NT; t++) {
            asw[t] = as_w[t * 16 + l16];
            adw[t] = ad_w[t * 16 + l16];
        }
#pragma unroll
        for (int sub = 0; sub < 2; sub++) {
#pragma unroll
            for (int rg = 0; rg < 4; rg++) {
                long row = r0 + w * 32 + sub * 16 + quad * 4 + rg;
                float s = 0.f, d = 0.f;
#pragma unroll
                for (int t = 0; t < NT; t++) {
                    float av = acc[sub][t][rg];
                    s += av * asw[t];
                    d += av * adw[t];
                }
                s += __shfl_xor(s, 1); s += __shfl_xor(s, 2); s += __shfl_xor(s, 4); s += __shfl_xor(s, 8);
                d += __shfl_xor(d, 1); d += __shfl_xor(d, 2); d += __shfl_xor(d, 4); d += __shfl_xor(d, 8);
                if (l16 == 0 && row < n) {
                    att_s[row] = s;
                    att_d[row] = d;
                }
            }
        }
    }
}

// ---------------------------------------------------------------------------
// bcount device body (LDS bucket histogram -> 1 global atomic per bucket).
// ---------------------------------------------------------------------------
__device__ __forceinline__ void bcount_dev(int bx, const int4* __restrict__ dst4v,
                                           int* __restrict__ bucketCount) {
    __shared__ int bh[NBUK];
    for (int i = threadIdx.x; i < NBUK; i += 256) bh[i] = 0;
    __syncthreads();
    int gtid = bx * 256 + threadIdx.x;
    for (int q = gtid; q < TQ; q += PB * 256) {
        int4 d;
        if (q < EQ) {
            d = dst4v[q];
        } else {
            int s0 = (q - EQ) * 4;       // self loops: dst = node id
            d.x = s0; d.y = s0 + 1; d.z = s0 + 2; d.w = s0 + 3;
        }
        atomicAdd(&bh[d.x >> 8], 1);
        atomicAdd(&bh[d.y >> 8], 1);
        atomicAdd(&bh[d.z >> 8], 1);
        atomicAdd(&bh[d.w >> 8], 1);
    }
    __syncthreads();
    for (int i = threadIdx.x; i < NBUK; i += 256)
        if (bh[i]) atomicAdd(&bucketCount[i], bh[i]);
}

// ---------------------------------------------------------------------------
// megaA: grid-partitioned fusion of the three independent front-end kernels:
// [0,GB) gemm(x_ppi)->packed xpc set 0; [GB,2GB) gemm(x_go)->set 1;
// [2GB,2GB+PB) bucket count. The latency-bound bcount blocks backfill CUs as
// gemm blocks retire -> its ~18us hides behind the gemms.
// ---------------------------------------------------------------------------
__global__ __launch_bounds__(256) void megaA(const float* __restrict__ x_ppi, const float* __restrict__ x_go,
                                             const int4* __restrict__ dst4v,
                                             const _Float16* __restrict__ w1T,
                                             const float* __restrict__ as1, const float* __restrict__ ad1,
                                             __half* __restrict__ xpc,
                                             float* __restrict__ att1s, float* __restrict__ att1d,
                                             int* __restrict__ bucketCount) {
    int bx = blockIdx.x;
    if (bx < GB) {
        gemm_dev<128, 128, true, 1, 0, 0>(bx, x_ppi, w1T, as1, ad1, xpc, att1s, att1d, NN);
    } else if (bx < 2 * GB) {
        gemm_dev<128, 128, true, 1, 0, 1>(bx - GB, x_go, w1T, as1, ad1, xpc, att1s, att1d, NN);
    } else {
        bcount_dev(bx - 2 * GB, dst4v, bucketCount);
    }
}

__global__ __launch_bounds__(256) void gemm_k2(const __half* __restrict__ hbuf,
                                               const _Float16* __restrict__ w2T,
                                               const float* __restrict__ as2, const float* __restrict__ ad2,
                                               __half* __restrict__ xp2,
                                               float* __restrict__ asr2, float* __restrict__ ads2) {
    gemm_dev<256, 64, false, 2, 1, 0>(blockIdx.x, hbuf, w2T, as2, ad2, xp2, asr2, ads2, NN);
}

// ---------------------------------------------------------------------------
// CSR build rest: bscan -> bplace -> per-bucket csr.
// ---------------------------------------------------------------------------
__global__ __launch_bounds__(512) void k_bscan(const int* __restrict__ bucketCount,
                                               int* __restrict__ bstart, int* __restrict__ gcur,
                                               int* __restrict__ rs) {
    __shared__ int sh[512];
    int t = threadIdx.x;
    int v = (t < NBUK) ? bucketCount[t] : 0;
    sh[t] = v;
    __syncthreads();
    for (int o = 1; o < 512; o <<= 1) {
        int u = (t >= o) ? sh[t - o] : 0;
        __syncthreads();
        sh[t] += u;
        __syncthreads();
    }
    if (t < NBUK) { bstart[t] = sh[t] - v; gcur[t] = sh[t] - v; }
    if (t == 0) { bstart[NBUK] = ET; rs[NN] = ET; }
}

__global__ __launch_bounds__(256) void k_bplace(const int4* __restrict__ src4v, const int4* __restrict__ dst4v,
                                                int* __restrict__ gcur, unsigned int* __restrict__ ebuf) {
    __shared__ int bh[NBUK];
    __shared__ int bbase[NBUK];
    for (int i = threadIdx.x; i < NBUK; i += 256) bh[i] = 0;
    __syncthreads();
    int gtid = blockIdx.x * 256 + threadIdx.x;

    int esrc[16];
    int emeta[16];   // (b<<21) | (ldst<<13) | lrank
#pragma unroll
    for (int it = 0; it < 4; it++) {
        int q = gtid + it * (PB * 256);
        bool valid = q < TQ;
        int4 s, d;
        if (valid) {
            if (q < EQ) { s = src4v[q]; d = dst4v[q]; }
            else { int s0 = (q - EQ) * 4; s.x = s0; s.y = s0 + 1; s.z = s0 + 2; s.w = s0 + 3; d = s; }
        } else {
            s.x = s.y = s.z = s.w = 0; d = s;
        }
        int ss[4] = {s.x, s.y, s.z, s.w};
        int dd[4] = {d.x, d.y, d.z, d.w};
#pragma unroll
        for (int k = 0; k < 4; k++) {
            int idx = it * 4 + k;
            if (valid) {
                int b = dd[k] >> 8, l = dd[k] & 255;
                int r = atomicAdd(&bh[b], 1);
                esrc[idx]  = ss[k];
                emeta[idx] = (b << 21) | (l << 13) | r;
            } else {
                emeta[idx] = -1;
            }
        }
    }
    __syncthreads();
    for (int i = threadIdx.x; i < NBUK; i += 256)
        bbase[i] = bh[i] ? atomicAdd(&gcur[i], bh[i]) : 0;
    __syncthreads();
#pragma unroll
    for (int e = 0; e < 16; e++) {
        int me = emeta[e];
        if (me >= 0) {
            int b = me >> 21, l = (me >> 13) & 255, r = me & 8191;
            ebuf[bbase[b] + r] = ((unsigned)l << 24) | (unsigned)esrc[e];
        }
    }
}

__global__ __launch_bounds__(256) void k_csr(const unsigned int* __restrict__ ebuf,
                                             const int* __restrict__ bstart,
                                             int* __restrict__ rs, int* __restrict__ csr) {
    __shared__ int hist[256];
    __shared__ int sh[256];
    __shared__ int cur[256];
    int b = blockIdx.x;
    int t = threadIdx.x;
    int e0 = bstart[b], e1 = bstart[b + 1];
    hist[t] = 0;
    __syncthreads();
    for (int j = e0 + t; j < e1; j += 256)
        atomicAdd(&hist[ebuf[j] >> 24], 1);
    __syncthreads();
    int v = hist[t];
    sh[t] = v;
    __syncthreads();
    for (int o = 1; o < 256; o <<= 1) {
        int u = (t >= o) ? sh[t - o] : 0;
        __syncthreads();
        sh[t] += u;
        __syncthreads();
    }
    int excl = sh[t] - v;
    cur[t] = excl;
    int v0 = b * 256;
    if (v0 + t < NN) rs[v0 + t] = e0 + excl;
    __syncthreads();
    for (int j = e0 + t; j < e1; j += 256) {
        unsigned int e = ebuf[j];
        int l = (int)(e >> 24);
        int r = atomicAdd(&cur[l], 1);
        csr[e0 + r] = (int)(e & 0x00FFFFFFu);
    }
}

// ---------------------------------------------------------------------------
// Packed single-pass conv1 (R3's measured-143.7us structure). One wave per
// dst node; two 32-lane halves each take edges j+2q+h; lane m (0..31) gathers
// the full 512B packed row via uint4 (channels 4m..4m+3 of BOTH sets).
// Attention weights inline from float2 tables ({p,g} per (node,head)):
// one 8B broadcast gather per edge. 8-edge full chunks (4 gathers in
// flight), 2-edge clamped tail. Cross-half combine via 10x shfl_xor(32).
// ---------------------------------------------------------------------------
__global__ __launch_bounds__(256) void conv1_packed(const int* __restrict__ rs, const int* __restrict__ csr,
                                                    const uint4* __restrict__ xpc,
                                                    const float2* __restrict__ att_s,  // [NN*4] {p,g}
                                                    const float2* __restrict__ att_d,  // [NN*4] {p,g}
                                                    const float* __restrict__ bias,
                                                    __half* __restrict__ out) {
    int v = blockIdx.x * 4 + (threadIdx.x >> 6);
    if (v >= NN) return;
    int lane = threadIdx.x & 63;
    int h = lane >> 5;                 // half-wave: 0 -> even edges, 1 -> odd edges
    int m = lane & 31;                 // channels 4m..4m+3 of both sets
    int hd = m >> 3;                   // head index
    int e0 = rs[v], e1 = rs[v + 1];

    float2 ad = att_d[v * 4 + hd];
    auto lrexp = [](float e) { e = (e > 0.f) ? e : NEG * e; return __expf(e); };

    float ap0 = 0.f, ap1 = 0.f, ap2 = 0.f, ap3 = 0.f;
    float ag0 = 0.f, ag1 = 0.f, ag2 = 0.f, ag3 = 0.f;
    float dp = 0.f, dg = 0.f;

    int j = e0;
    // full chunks: 8 edges, 4 gathers in flight, no predication
    for (; j + 8 <= e1; j += 8) {
        int s[4]; float2 av[4]; uint4 r[4];
#pragma unroll
        for (int q = 0; q < 4; q++) s[q] = csr[j + 2 * q + h];
#pragma unroll
        for (int q = 0; q < 4; q++) av[q] = att_s[s[q] * 4 + hd];
#pragma unroll
        for (int q = 0; q < 4; q++) r[q] = xpc[(long)s[q] * 32 + m];
#pragma unroll
        for (int q = 0; q < 4; q++) {
            float wx = lrexp(av[q].x + ad.x);
            float wy = lrexp(av[q].y + ad.y);
            dp += wx; dg += wy;
            float2 p01 = __half22float2(*(__half2*)&r[q].x);
            float2 g01 = __half22float2(*(__half2*)&r[q].y);
            float2 p23 = __half22float2(*(__half2*)&r[q].z);
            float2 g23 = __half22float2(*(__half2*)&r[q].w);
            ap0 += wx * p01.x; ap1 += wx * p01.y; ap2 += wx * p23.x; ap3 += wx * p23.y;
            ag0 += wy * g01.x; ag1 += wy * g01.y; ag2 += wy * g23.x; ag3 += wy * g23.y;
        }
    }
    // tail: 2 edges per iteration, clamped duplicate gathers with zero weight
    for (; j < e1; j += 2) {
        int jj = j + h;
        int jc = (jj < e1) ? jj : (e1 - 1);
        bool ok = jj < e1;
        int s = csr[jc];
        float2 av = att_s[s * 4 + hd];
        uint4 r = xpc[(long)s * 32 + m];
        float wx = ok ? lrexp(av.x + ad.x) : 0.f;
        float wy = ok ? lrexp(av.y + ad.y) : 0.f;
        dp += wx; dg += wy;
        float2 p01 = __half22float2(*(__half2*)&r.x);
        float2 g01 = __half22float2(*(__half2*)&r.y);
        float2 p23 = __half22float2(*(__half2*)&r.z);
        float2 g23 = __half22float2(*(__half2*)&r.w);
        ap0 += wx * p01.x; ap1 += wx * p01.y; ap2 += wx * p23.x; ap3 += wx * p23.y;
        ag0 += wy * g01.x; ag1 += wy * g01.y; ag2 += wy * g23.x; ag3 += wy * g23.y;
    }

    // combine the two halves (independent edge subsets)
    ap0 += __shfl_xor(ap0, 32); ap1 += __shfl_xor(ap1, 32);
    ap2 += __shfl_xor(ap2, 32); ap3 += __shfl_xor(ap3, 32);
    ag0 += __shfl_xor(ag0, 32); ag1 += __shfl_xor(ag1, 32);
    ag2 += __shfl_xor(ag2, 32); ag3 += __shfl_xor(ag3, 32);
    dp  += __shfl_xor(dp, 32);  dg  += __shfl_xor(dg, 32);

    float ivp = 1.0f / dp, ivg = 1.0f / dg;
    int c0 = 4 * m;
    float4 b4 = *(const float4*)&bias[c0];
    // half 0 writes the p-set, half 1 writes the g-set (same channels)
    float inv = h ? ivg : ivp;
    float a0 = h ? ag0 : ap0;
    float a1 = h ? ag1 : ap1;
    float a2 = h ? ag2 : ap2;
    float a3 = h ? ag3 : ap3;
    __half2 o01 = __floats2half2_rn(fmaxf(a0 * inv + b4.x, 0.f), fmaxf(a1 * inv + b4.y, 0.f));
    __half2 o23 = __floats2half2_rn(fmaxf(a2 * inv + b4.z, 0.f), fmaxf(a3 * inv + b4.w, 0.f));
    uint2 st;
    st.x = *(unsigned int*)&o01;
    st.y = *(unsigned int*)&o23;
    *(uint2*)(out + (long)v * 256 + h * 128 + c0) = st;
}

// ---------------------------------------------------------------------------
// Single-pass conv2 edge kernel (H=1, C=64, fp16 xp). Weight inline from
// asrc[s] (400KB) + adst[v] register. Quarter-waves; 16-edge full chunks.
// ---------------------------------------------------------------------------
__global__ __launch_bounds__(256) void conv2_edge(const int* __restrict__ rs, const int* __restrict__ csr,
                                                  const __half* __restrict__ xp,
                                                  const float* __restrict__ asrc,
                                                  const float* __restrict__ adst,
                                                  const float* __restrict__ bias,
                                                  float* __restrict__ out) {
    int v = blockIdx.x * 4 + (threadIdx.x >> 6);
    if (v >= NN) return;
    int lane = threadIdx.x & 63;
    int qw = lane >> 4;                // quarter-wave: edge offset
    int m = lane & 15;                 // channels 4m..4m+3
    int e0 = rs[v], e1 = rs[v + 1];
    const uint2* xp2 = (const uint2*)xp;

    float adv = adst[v];
    auto lrexp = [](float e) { e = (e > 0.f) ? e : NEG * e; return __expf(e); };

    float a0 = 0.f, a1 = 0.f, a2 = 0.f, a3 = 0.f, d = 0.f;

    int j = e0;
    // full chunks: 16 edges, 4 gathers in flight, no predication
    for (; j + 16 <= e1; j += 16) {
        int s[4]; float av[4]; uint2 r[4];
#pragma unroll
        for (int k = 0; k < 4; k++) s[k] = csr[j + 4 * k + qw];
#pragma unroll
        for (int k = 0; k < 4; k++) av[k] = asrc[s[k]];
#pragma unroll
        for (int k = 0; k < 4; k++) r[k] = xp2[(long)s[k] * 16 + m];
#pragma unroll
        for (int k = 0; k < 4; k++) {
            float w = lrexp(av[k] + adv);
            d += w;
            float2 x01 = __half22float2(*(__half2*)&r[k].x);
            float2 x23 = __half22float2(*(__half2*)&r[k].y);
            a0 += w * x01.x; a1 += w * x01.y;
            a2 += w * x23.x; a3 += w * x23.y;
        }
    }
    // tail: 4 edges per iteration, clamped
    for (; j < e1; j += 4) {
        int jj = j + qw;
        int jc = (jj < e1) ? jj : (e1 - 1);
        int s = csr[jc];
        float av = asrc[s];
        uint2 r = xp2[(long)s * 16 + m];
        float w = (jj < e1) ? lrexp(av + adv) : 0.f;
        d += w;
        float2 x01 = __half22float2(*(__half2*)&r.x);
        float2 x23 = __half22float2(*(__half2*)&r.y);
        a0 += w * x01.x; a1 += w * x01.y;
        a2 += w * x23.x; a3 += w * x23.y;
    }

    // combine the four quarters
    a0 += __shfl_xor(a0, 16); a1 += __shfl_xor(a1, 16);
    a2 += __shfl_xor(a2, 16); a3 += __shfl_xor(a3, 16);
    d  += __shfl_xor(d, 16);
    a0 += __shfl_xor(a0, 32); a1 += __shfl_xor(a1, 32);
    a2 += __shfl_xor(a2, 32); a3 += __shfl_xor(a3, 32);
    d  += __shfl_xor(d, 32);

    if (qw == 0) {
        float inv = 1.0f / d;
        float4 b4 = *(const float4*)&bias[4 * m];
        float4 o;
        o.x = a0 * inv + b4.x;
        o.y = a1 * inv + b4.y;
        o.z = a2 * inv + b4.z;
        o.w = a3 * inv + b4.w;
        *(float4*)&out[(long)v * 64 + 4 * m] = o;
    }
}

// ---------------------------------------------------------------------------
// Launch
// ---------------------------------------------------------------------------
extern "C" void kernel_launch(void* const* d_in, const int* in_sizes, int n_in,
                              void* d_out, int out_size, void* d_ws, size_t ws_size,
                              hipStream_t stream) {
    const float* x_ppi = (const float*)d_in[0];
    const float* x_go  = (const float*)d_in[1];
    const int*   ei    = (const int*)d_in[2];
    const float* W1    = (const float*)d_in[3];
    const float* as1   = (const float*)d_in[4];
    const float* ad1   = (const float*)d_in[5];
    const float* b1    = (const float*)d_in[6];
    const float* W2    = (const float*)d_in[7];
    const float* as2   = (const float*)d_in[8];
    const float* ad2   = (const float*)d_in[9];
    const float* b2    = (const float*)d_in[10];
    float* out = (float*)d_out;

    char* ws = (char*)d_ws;
    size_t off = 0;
    auto alloc = [&](size_t bytes) -> void* {
        void* p = ws + off;
        off = (off + bytes + 255) & ~(size_t)255;
        return p;
    };
    int* bucketCount = (int*)alloc((size_t)NBUK * 4);
    int* bstart      = (int*)alloc((size_t)(NBUK + 1) * 4);
    int* gcur        = (int*)alloc((size_t)NBUK * 4);
    unsigned int* ebuf = (unsigned int*)alloc((size_t)ET * 4);
    int* rs      = (int*)alloc((size_t)(NN + 1) * 4);
    int* csr     = (int*)alloc((size_t)ET * 4);
    _Float16* w1T = (_Float16*)alloc((size_t)128 * 128 * 2);
    _Float16* w2T = (_Float16*)alloc((size_t)64 * 256 * 2);
    __half* xpc  = (__half*)alloc((size_t)NN * 256 * 2);   // packed {p0,p1,g0,g1} fp16
    __half* xp2  = (__half*)alloc((size_t)NN * 64 * 2);    // conv2 features fp16
    float* att1s = (float*)alloc((size_t)NN * 4 * 8);      // float2 {p,g} per (node,head)
    float* att1d = (float*)alloc((size_t)NN * 4 * 8);
    float* asr2  = (float*)alloc((size_t)NN * 4);
    float* ads2  = (float*)alloc((size_t)NN * 4);
    __half* hbuf = (__half*)alloc((size_t)NN * 256 * 2);   // conv1 output, fp16
    (void)ws_size; (void)in_sizes; (void)n_in; (void)out_size;

    // 1) weight prep + bucketCount zero
    k_wprep0<<<128, 256, 0, stream>>>(W1, W2, w1T, w2T, bucketCount);
    // 2) fused front-end: two packed GEMMs (+attn epilogues) + bucket count
    megaA<<<2 * GB + PB, 256, 0, stream>>>(x_ppi, x_go, (const int4*)(ei + EE),
                                           w1T, as1, ad1, xpc, att1s, att1d, bucketCount);
    // 3-5) CSR build rest
    k_bscan<<<1, 512, 0, stream>>>(bucketCount, bstart, gcur, rs);
    k_bplace<<<PB, 256, 0, stream>>>((const int4*)ei, (const int4*)(ei + EE), gcur, ebuf);
    k_csr<<<NBUK, 256, 0, stream>>>(ebuf, bstart, rs, csr);
    // 6) packed single-pass conv1 with inline attention
    conv1_packed<<<NN / 4, 256, 0, stream>>>(rs, csr, (const uint4*)xpc,
                                             (const float2*)att1s, (const float2*)att1d, b1, hbuf);
    // 7) layer-2 GEMM with fused H=1 attention
    gemm_k2<<<GB, 256, 0, stream>>>(hbuf, w2T, as2, ad2, xp2, asr2, ads2);
    // 8) conv2
    conv2_edge<<<NN / 4, 256, 0, stream>>>(rs, csr, xp2, asr2, ads2, b2, out);
}